// Round 1
// baseline (11889.306 us; speedup 1.0000x reference)
//
#include <hip/hip_runtime.h>

#define N_NODES 64000
#define BN_EPS 1e-5f

static inline int cdiv(long long a, int b) { return (int)((a + b - 1) / b); }

// ---- degree counting (as float, values are small integers) ----
__global__ void degree_kernel(const int* __restrict__ src, const int* __restrict__ dst,
                              float* rs_out, float* rs_in, int E) {
  int i = blockIdx.x * blockDim.x + threadIdx.x;
  if (i < E) {
    atomicAdd(&rs_out[src[i]], 1.0f);
    atomicAdd(&rs_in[dst[i]], 1.0f);
  }
}

__global__ void rsqrt_clip_kernel(float* p, int n) {
  int i = blockIdx.x * blockDim.x + threadIdx.x;
  if (i < n) p[i] = rsqrtf(fmaxf(p[i], 1.0f));
}

// ---- edge scatter: agg[dst] += h[src] * rs_out[src], 4 feats per thread ----
template<int DIN>
__global__ void scatter_kernel(const float* __restrict__ h, const int* __restrict__ src,
                               const int* __restrict__ dst, const float* __restrict__ rs_out,
                               float* agg, int E) {
  constexpr int C = DIN / 4;
  int tid = blockIdx.x * blockDim.x + threadIdx.x;
  int total = E * C;
  if (tid >= total) return;
  int e = tid / C, c = tid - e * C;
  int s = src[e], d = dst[e];
  float w = rs_out[s];
  float4 v = ((const float4*)h)[(long long)s * C + c];
  float* o = agg + (long long)d * DIN + c * 4;
  atomicAdd(o + 0, v.x * w);
  atomicAdd(o + 1, v.y * w);
  atomicAdd(o + 2, v.z * w);
  atomicAdd(o + 3, v.w * w);
}

// ---- out[r,j] (+)= rs[r] * (A[r,:] @ W[:,j]) + b[j] ----
template<int DIN, int DOUT>
__global__ void matmul_kernel(const float* __restrict__ A, const float* __restrict__ rs,
                              const float* __restrict__ W, const float* __restrict__ b,
                              float* __restrict__ out, int first) {
  int idx = blockIdx.x * blockDim.x + threadIdx.x;
  if (idx >= N_NODES * DOUT) return;
  int r = idx / DOUT, j = idx - r * DOUT;
  const float4* a4 = (const float4*)(A + (long long)r * DIN);
  float acc = 0.f;
#pragma unroll
  for (int k4 = 0; k4 < DIN / 4; ++k4) {
    float4 v = a4[k4];
    acc = fmaf(v.x, W[(k4 * 4 + 0) * DOUT + j], acc);
    acc = fmaf(v.y, W[(k4 * 4 + 1) * DOUT + j], acc);
    acc = fmaf(v.z, W[(k4 * 4 + 2) * DOUT + j], acc);
    acc = fmaf(v.w, W[(k4 * 4 + 3) * DOUT + j], acc);
  }
  float s = rs ? rs[r] : 1.0f;
  float val = acc * s + b[j];
  if (first) out[idx] = val;
  else out[idx] += val;
}

// ---- batchnorm column stats: sum and sum-of-squares per feature ----
template<int D>
__global__ void bn_stats_kernel(const float* __restrict__ h, float* __restrict__ stats) {
  __shared__ float s0[D], s1[D];
  for (int i = threadIdx.x; i < D; i += blockDim.x) { s0[i] = 0.f; s1[i] = 0.f; }
  __syncthreads();
  int n = N_NODES * D;
  int stride = gridDim.x * blockDim.x;
  for (int i = blockIdx.x * blockDim.x + threadIdx.x; i < n; i += stride) {
    float v = h[i];
    int f = i % D;
    atomicAdd(&s0[f], v);
    atomicAdd(&s1[f], v * v);
  }
  __syncthreads();
  for (int i = threadIdx.x; i < D; i += blockDim.x) {
    atomicAdd(&stats[i], s0[i]);
    atomicAdd(&stats[D + i], s1[i]);
  }
}

template<int D>
__global__ void bn_finalize_kernel(const float* __restrict__ stats, const float* __restrict__ g,
                                   const float* __restrict__ be, float* scale, float* shift) {
  int f = threadIdx.x;
  if (f < D) {
    float mean = stats[f] * (1.0f / N_NODES);
    float var = stats[D + f] * (1.0f / N_NODES) - mean * mean;
    float rstd = rsqrtf(var + BN_EPS);
    float sc = g[f] * rstd;
    scale[f] = sc;
    shift[f] = be[f] - mean * sc;
  }
}

template<int D>
__global__ void bn_apply_relu_kernel(float* __restrict__ h, const float* __restrict__ scale,
                                     const float* __restrict__ shift) {
  int i = blockIdx.x * blockDim.x + threadIdx.x;
  int n = N_NODES * D;
  if (i < n) {
    int f = i % D;
    float v = h[i] * scale[f] + shift[f];
    h[i] = v > 0.f ? v : 0.f;
  }
}

extern "C" void kernel_launch(void* const* d_in, const int* in_sizes, int n_in,
                              void* d_out, int out_size, void* d_ws, size_t ws_size,
                              hipStream_t stream) {
  const int N = N_NODES;
  const float* x = (const float*)d_in[0];
  const int* src[3] = {(const int*)d_in[1], (const int*)d_in[3], (const int*)d_in[5]};
  const int* dst[3] = {(const int*)d_in[2], (const int*)d_in[4], (const int*)d_in[6]};
  const int E[3] = {in_sizes[1], in_sizes[3], in_sizes[5]};

  const float* w0[3] = {(const float*)d_in[7], (const float*)d_in[9], (const float*)d_in[11]};
  const float* b0[3] = {(const float*)d_in[8], (const float*)d_in[10], (const float*)d_in[12]};
  const float* bn0_g = (const float*)d_in[13];
  const float* bn0_b = (const float*)d_in[14];
  const float* fc0_w = (const float*)d_in[15];
  const float* fc0_b = (const float*)d_in[16];
  const float* w1[3] = {(const float*)d_in[17], (const float*)d_in[19], (const float*)d_in[21]};
  const float* b1[3] = {(const float*)d_in[18], (const float*)d_in[20], (const float*)d_in[22]};
  const float* bn1_g = (const float*)d_in[23];
  const float* bn1_b = (const float*)d_in[24];
  const float* fc1_w = (const float*)d_in[25];
  const float* fc1_b = (const float*)d_in[26];

  // workspace layout (floats)
  float* ws = (float*)d_ws;
  float* rs = ws;                       // 6*N: [knn_out, knn_in, sph_out, sph_in, seq_out, seq_in]
  float* agg = rs + 6 * N;              // N*96 max
  float* hsum = agg + (long long)N * 96;   // N*128 max
  float* h1 = hsum + (long long)N * 128;   // N*96
  float* stats = h1 + (long long)N * 96;   // 2*128
  float* scale = stats + 256;           // 128
  float* shift = scale + 128;           // 128

  const int B = 256;

  // ---- degrees (shared by both layers) ----
  hipMemsetAsync(rs, 0, 6 * N * sizeof(float), stream);
  for (int e = 0; e < 3; ++e)
    degree_kernel<<<cdiv(E[e], B), B, 0, stream>>>(src[e], dst[e], rs + (2 * e) * N, rs + (2 * e + 1) * N, E[e]);
  rsqrt_clip_kernel<<<cdiv(6 * N, B), B, 0, stream>>>(rs, 6 * N);

  // ---- layer 0: aggregate x (D=64) per type, matmul 64->96 accumulate ----
  for (int e = 0; e < 3; ++e) {
    hipMemsetAsync(agg, 0, (size_t)N * 64 * sizeof(float), stream);
    scatter_kernel<64><<<cdiv((long long)E[e] * 16, B), B, 0, stream>>>(
        x, src[e], dst[e], rs + (2 * e) * N, agg, E[e]);
    matmul_kernel<64, 96><<<cdiv((long long)N * 96, B), B, 0, stream>>>(
        agg, rs + (2 * e + 1) * N, w0[e], b0[e], hsum, e == 0 ? 1 : 0);
  }
  // BN -> ReLU -> FC (96->96)
  hipMemsetAsync(stats, 0, 2 * 96 * sizeof(float), stream);
  bn_stats_kernel<96><<<2048, B, 0, stream>>>(hsum, stats);
  bn_finalize_kernel<96><<<1, 128, 0, stream>>>(stats, bn0_g, bn0_b, scale, shift);
  bn_apply_relu_kernel<96><<<cdiv((long long)N * 96, B), B, 0, stream>>>(hsum, scale, shift);
  matmul_kernel<96, 96><<<cdiv((long long)N * 96, B), B, 0, stream>>>(
      hsum, nullptr, fc0_w, fc0_b, h1, 1);

  // ---- layer 1: aggregate h1 (D=96) per type, matmul 96->128 accumulate ----
  for (int e = 0; e < 3; ++e) {
    hipMemsetAsync(agg, 0, (size_t)N * 96 * sizeof(float), stream);
    scatter_kernel<96><<<cdiv((long long)E[e] * 24, B), B, 0, stream>>>(
        h1, src[e], dst[e], rs + (2 * e) * N, agg, E[e]);
    matmul_kernel<96, 128><<<cdiv((long long)N * 128, B), B, 0, stream>>>(
        agg, rs + (2 * e + 1) * N, w1[e], b1[e], hsum, e == 0 ? 1 : 0);
  }
  // BN -> ReLU -> FC (128->128) -> d_out
  hipMemsetAsync(stats, 0, 2 * 128 * sizeof(float), stream);
  bn_stats_kernel<128><<<2048, B, 0, stream>>>(hsum, stats);
  bn_finalize_kernel<128><<<1, 128, 0, stream>>>(stats, bn1_g, bn1_b, scale, shift);
  bn_apply_relu_kernel<128><<<cdiv((long long)N * 128, B), B, 0, stream>>>(hsum, scale, shift);
  matmul_kernel<128, 128><<<cdiv((long long)N * 128, B), B, 0, stream>>>(
      hsum, nullptr, fc1_w, fc1_b, (float*)d_out, 1);
}

// Round 2
// 2350.082 us; speedup vs baseline: 5.0591x; 5.0591x over previous
//
#include <hip/hip_runtime.h>

#define N_NODES 64000
#define BN_EPS 1e-5f

static inline int cdiv(long long a, int b) { return (int)((a + b - 1) / b); }

// ---- count out/in degrees (int atomics) ----
__global__ void count_kernel(const int* __restrict__ src, const int* __restrict__ dst,
                             int* cnt_out, int* cnt_in, int E) {
  int i = blockIdx.x * blockDim.x + threadIdx.x;
  if (i < E) {
    atomicAdd(&cnt_out[src[i]], 1);
    atomicAdd(&cnt_in[dst[i]], 1);
  }
}

// ---- exclusive prefix sum over N_NODES counts (single block) ----
__global__ void scan_kernel(const int* __restrict__ cnt, int* __restrict__ row_ptr,
                            int* __restrict__ cursor, int E) {
  const int T = 1024;
  __shared__ int part[T];
  int t = threadIdx.x;
  const int chunk = (N_NODES + T - 1) / T;
  int lo = t * chunk, hi = min(lo + chunk, N_NODES);
  int s = 0;
  for (int i = lo; i < hi; ++i) s += cnt[i];
  part[t] = s;
  __syncthreads();
  for (int off = 1; off < T; off <<= 1) {
    int add = (t >= off) ? part[t - off] : 0;
    __syncthreads();
    part[t] += add;
    __syncthreads();
  }
  int base = (t == 0) ? 0 : part[t - 1];
  for (int i = lo; i < hi; ++i) {
    row_ptr[i] = base;
    cursor[i] = base;
    base += cnt[i];
  }
  if (t == T - 1) row_ptr[N_NODES] = E;
}

// ---- scatter edges into dst-sorted order ----
__global__ void fill_kernel(const int* __restrict__ src, const int* __restrict__ dst,
                            int* cursor, int* __restrict__ es, int E) {
  int i = blockIdx.x * blockDim.x + threadIdx.x;
  if (i < E) {
    int p = atomicAdd(&cursor[dst[i]], 1);
    es[p] = src[i];
  }
}

// ---- in-place int count -> float rsqrt(max(cnt,1)) ----
__global__ void rsqrt_inplace_kernel(void* buf, int n) {
  int i = blockIdx.x * blockDim.x + threadIdx.x;
  if (i < n) {
    int c = ((const int*)buf)[i];
    ((float*)buf)[i] = rsqrtf(fmaxf((float)c, 1.0f));
  }
}

// ---- pull aggregation: one wave per node, lanes = features ----
// agg[d][f] = rs_in[d] * sum_e rs_out[s_e] * h[s_e][f]
template<int D>
__global__ void gather_kernel(const float* __restrict__ h, const int* __restrict__ row_ptr,
                              const int* __restrict__ es, const float* __restrict__ rs_out,
                              const float* __restrict__ rs_in, float* __restrict__ agg) {
  int wid = (blockIdx.x * blockDim.x + threadIdx.x) >> 6;
  int lane = threadIdx.x & 63;
  if (wid >= N_NODES) return;
  int lo = row_ptr[wid], hi = row_ptr[wid + 1];
  float acc0 = 0.f, acc1 = 0.f;
  const bool two = (D > 64) && (lane < D - 64);
  int e = lo;
  for (; e + 1 < hi; e += 2) {
    int s0 = es[e], s1 = es[e + 1];
    float w0 = rs_out[s0], w1 = rs_out[s1];
    acc0 += w0 * h[s0 * D + lane];
    acc0 += w1 * h[s1 * D + lane];
    if (D > 64) {
      if (two) {
        acc1 += w0 * h[s0 * D + 64 + lane];
        acc1 += w1 * h[s1 * D + 64 + lane];
      }
    }
  }
  if (e < hi) {
    int s0 = es[e];
    float w0 = rs_out[s0];
    acc0 += w0 * h[s0 * D + lane];
    if (D > 64) { if (two) acc1 += w0 * h[s0 * D + 64 + lane]; }
  }
  float ri = rs_in[wid];
  agg[wid * D + lane] = acc0 * ri;
  if (D > 64) { if (two) agg[wid * D + 64 + lane] = acc1 * ri; }
}

// ---- out[r,j] (+)= A[r,:] @ W[:,j] + b[j] ----
template<int DIN, int DOUT>
__global__ void matmul_kernel(const float* __restrict__ A, const float* __restrict__ W,
                              const float* __restrict__ b, float* __restrict__ out, int first) {
  int idx = blockIdx.x * blockDim.x + threadIdx.x;
  if (idx >= N_NODES * DOUT) return;
  int r = idx / DOUT, j = idx - r * DOUT;
  const float4* a4 = (const float4*)(A + r * DIN);
  float acc = b[j];
#pragma unroll
  for (int k4 = 0; k4 < DIN / 4; ++k4) {
    float4 v = a4[k4];
    acc = fmaf(v.x, W[(k4 * 4 + 0) * DOUT + j], acc);
    acc = fmaf(v.y, W[(k4 * 4 + 1) * DOUT + j], acc);
    acc = fmaf(v.z, W[(k4 * 4 + 2) * DOUT + j], acc);
    acc = fmaf(v.w, W[(k4 * 4 + 3) * DOUT + j], acc);
  }
  if (first) out[idx] = acc;
  else out[idx] += acc;
}

// ---- batchnorm column stats: sum and sum-of-squares per feature ----
template<int D>
__global__ void bn_stats_kernel(const float* __restrict__ h, float* __restrict__ stats) {
  __shared__ float s0[D], s1[D];
  for (int i = threadIdx.x; i < D; i += blockDim.x) { s0[i] = 0.f; s1[i] = 0.f; }
  __syncthreads();
  int n = N_NODES * D;
  int stride = gridDim.x * blockDim.x;
  for (int i = blockIdx.x * blockDim.x + threadIdx.x; i < n; i += stride) {
    float v = h[i];
    int f = i % D;
    atomicAdd(&s0[f], v);
    atomicAdd(&s1[f], v * v);
  }
  __syncthreads();
  for (int i = threadIdx.x; i < D; i += blockDim.x) {
    atomicAdd(&stats[i], s0[i]);
    atomicAdd(&stats[D + i], s1[i]);
  }
}

template<int D>
__global__ void bn_finalize_kernel(const float* __restrict__ stats, const float* __restrict__ g,
                                   const float* __restrict__ be, float* scale, float* shift) {
  int f = threadIdx.x;
  if (f < D) {
    float mean = stats[f] * (1.0f / N_NODES);
    float var = stats[D + f] * (1.0f / N_NODES) - mean * mean;
    float rstd = rsqrtf(var + BN_EPS);
    float sc = g[f] * rstd;
    scale[f] = sc;
    shift[f] = be[f] - mean * sc;
  }
}

// ---- fused BN->ReLU->FC: out = relu(A*scale+shift) @ W + b ----
template<int DIN, int DOUT>
__global__ void fc_bnrelu_kernel(const float* __restrict__ A, const float* __restrict__ scale,
                                 const float* __restrict__ shift, const float* __restrict__ W,
                                 const float* __restrict__ b, float* __restrict__ out) {
  int idx = blockIdx.x * blockDim.x + threadIdx.x;
  if (idx >= N_NODES * DOUT) return;
  int r = idx / DOUT, j = idx - r * DOUT;
  const float4* a4 = (const float4*)(A + r * DIN);
  float acc = b[j];
#pragma unroll
  for (int k4 = 0; k4 < DIN / 4; ++k4) {
    float4 v = a4[k4];
    int k = k4 * 4;
    float x0 = fmaxf(fmaf(v.x, scale[k + 0], shift[k + 0]), 0.f);
    float x1 = fmaxf(fmaf(v.y, scale[k + 1], shift[k + 1]), 0.f);
    float x2 = fmaxf(fmaf(v.z, scale[k + 2], shift[k + 2]), 0.f);
    float x3 = fmaxf(fmaf(v.w, scale[k + 3], shift[k + 3]), 0.f);
    acc = fmaf(x0, W[(k + 0) * DOUT + j], acc);
    acc = fmaf(x1, W[(k + 1) * DOUT + j], acc);
    acc = fmaf(x2, W[(k + 2) * DOUT + j], acc);
    acc = fmaf(x3, W[(k + 3) * DOUT + j], acc);
  }
  out[idx] = acc;
}

extern "C" void kernel_launch(void* const* d_in, const int* in_sizes, int n_in,
                              void* d_out, int out_size, void* d_ws, size_t ws_size,
                              hipStream_t stream) {
  const int N = N_NODES;
  const float* x = (const float*)d_in[0];
  const int* src[3] = {(const int*)d_in[1], (const int*)d_in[3], (const int*)d_in[5]};
  const int* dst[3] = {(const int*)d_in[2], (const int*)d_in[4], (const int*)d_in[6]};
  const int E[3] = {in_sizes[1], in_sizes[3], in_sizes[5]};
  const int E_tot = E[0] + E[1] + E[2];

  const float* w0[3] = {(const float*)d_in[7], (const float*)d_in[9], (const float*)d_in[11]};
  const float* b0[3] = {(const float*)d_in[8], (const float*)d_in[10], (const float*)d_in[12]};
  const float* bn0_g = (const float*)d_in[13];
  const float* bn0_b = (const float*)d_in[14];
  const float* fc0_w = (const float*)d_in[15];
  const float* fc0_b = (const float*)d_in[16];
  const float* w1[3] = {(const float*)d_in[17], (const float*)d_in[19], (const float*)d_in[21]};
  const float* b1[3] = {(const float*)d_in[18], (const float*)d_in[20], (const float*)d_in[22]};
  const float* bn1_g = (const float*)d_in[23];
  const float* bn1_b = (const float*)d_in[24];
  const float* fc1_w = (const float*)d_in[25];
  const float* fc1_b = (const float*)d_in[26];

  // ---- workspace layout ----
  // cnt/rs: 6*N words, per type: [out, in]; ints during count, floats after rsqrt_inplace
  char* wsb = (char*)d_ws;
  int* cnt = (int*)wsb;                       wsb += (size_t)6 * N * 4;
  int* row_ptr = (int*)wsb;                   wsb += (size_t)3 * (N + 1) * 4;
  int* cursor = (int*)wsb;                    wsb += (size_t)3 * N * 4;
  int* es = (int*)wsb;                        wsb += (size_t)E_tot * 4;
  float* agg = (float*)wsb;                   wsb += (size_t)N * 96 * 4;
  float* hsum = (float*)wsb;                  wsb += (size_t)N * 128 * 4;
  float* h1 = (float*)wsb;                    wsb += (size_t)N * 96 * 4;
  float* stats = (float*)wsb;                 wsb += 256 * 4;
  float* scale = (float*)wsb;                 wsb += 128 * 4;
  float* shift = (float*)wsb;                 wsb += 128 * 4;
  float* rs = (float*)cnt;  // aliased after rsqrt_inplace

  int es_off[3] = {0, E[0], E[0] + E[1]};
  const int B = 256;

  // ---- CSR build + degrees ----
  hipMemsetAsync(cnt, 0, (size_t)6 * N * 4, stream);
  for (int e = 0; e < 3; ++e)
    count_kernel<<<cdiv(E[e], B), B, 0, stream>>>(src[e], dst[e], cnt + (2 * e) * N,
                                                  cnt + (2 * e + 1) * N, E[e]);
  for (int e = 0; e < 3; ++e)
    scan_kernel<<<1, 1024, 0, stream>>>(cnt + (2 * e + 1) * N, row_ptr + e * (N + 1),
                                        cursor + e * N, E[e]);
  for (int e = 0; e < 3; ++e)
    fill_kernel<<<cdiv(E[e], B), B, 0, stream>>>(src[e], dst[e], cursor + e * N,
                                                 es + es_off[e], E[e]);
  rsqrt_inplace_kernel<<<cdiv(6 * N, B), B, 0, stream>>>(cnt, 6 * N);

  // ---- layer 0: gather x (D=64) per type, matmul 64->96 accumulate ----
  for (int e = 0; e < 3; ++e) {
    gather_kernel<64><<<cdiv((long long)N * 64, B), B, 0, stream>>>(
        x, row_ptr + e * (N + 1), es + es_off[e], rs + (2 * e) * N, rs + (2 * e + 1) * N, agg);
    matmul_kernel<64, 96><<<cdiv((long long)N * 96, B), B, 0, stream>>>(
        agg, w0[e], b0[e], hsum, e == 0 ? 1 : 0);
  }
  hipMemsetAsync(stats, 0, 2 * 96 * 4, stream);
  bn_stats_kernel<96><<<2048, B, 0, stream>>>(hsum, stats);
  bn_finalize_kernel<96><<<1, 128, 0, stream>>>(stats, bn0_g, bn0_b, scale, shift);
  fc_bnrelu_kernel<96, 96><<<cdiv((long long)N * 96, B), B, 0, stream>>>(
      hsum, scale, shift, fc0_w, fc0_b, h1);

  // ---- layer 1: gather h1 (D=96) per type, matmul 96->128 accumulate ----
  for (int e = 0; e < 3; ++e) {
    gather_kernel<96><<<cdiv((long long)N * 64, B), B, 0, stream>>>(
        h1, row_ptr + e * (N + 1), es + es_off[e], rs + (2 * e) * N, rs + (2 * e + 1) * N, agg);
    matmul_kernel<96, 128><<<cdiv((long long)N * 128, B), B, 0, stream>>>(
        agg, w1[e], b1[e], hsum, e == 0 ? 1 : 0);
  }
  hipMemsetAsync(stats, 0, 2 * 128 * 4, stream);
  bn_stats_kernel<128><<<2048, B, 0, stream>>>(hsum, stats);
  bn_finalize_kernel<128><<<1, 128, 0, stream>>>(stats, bn1_g, bn1_b, scale, shift);
  fc_bnrelu_kernel<128, 128><<<cdiv((long long)N * 128, B), B, 0, stream>>>(
      hsum, scale, shift, fc1_w, fc1_b, (float*)d_out);
}

// Round 3
// 1245.360 us; speedup vs baseline: 9.5469x; 1.8871x over previous
//
#include <hip/hip_runtime.h>
#include <hip/hip_bf16.h>

#define N_NODES 64000
#define BN_EPS 1e-5f

typedef __attribute__((ext_vector_type(8))) short short8v;   // 8 bf16 (4 VGPRs)
typedef __attribute__((ext_vector_type(4))) float f32x4;

static inline int cdiv(long long a, int b) { return (int)((a + b - 1) / b); }

__device__ inline float bf2f(unsigned short u) {
  union { unsigned int i; float f; } v; v.i = ((unsigned int)u) << 16; return v.f;
}
__device__ inline unsigned short f2bf(float f) {
  __hip_bfloat16 h = __float2bfloat16(f);
  return *reinterpret_cast<unsigned short*>(&h);
}

// ---- count out/in degrees (int atomics) ----
__global__ void count_kernel(const int* __restrict__ src, const int* __restrict__ dst,
                             int* cnt_out, int* cnt_in, int E) {
  int i = blockIdx.x * blockDim.x + threadIdx.x;
  if (i < E) {
    atomicAdd(&cnt_out[src[i]], 1);
    atomicAdd(&cnt_in[dst[i]], 1);
  }
}

// ---- exclusive prefix sum over N_NODES counts (single block) ----
__global__ void scan_kernel(const int* __restrict__ cnt, int* __restrict__ row_ptr,
                            int* __restrict__ cursor, int E) {
  const int T = 1024;
  __shared__ int part[T];
  int t = threadIdx.x;
  const int chunk = (N_NODES + T - 1) / T;
  int lo = t * chunk, hi = min(lo + chunk, N_NODES);
  int s = 0;
  for (int i = lo; i < hi; ++i) s += cnt[i];
  part[t] = s;
  __syncthreads();
  for (int off = 1; off < T; off <<= 1) {
    int add = (t >= off) ? part[t - off] : 0;
    __syncthreads();
    part[t] += add;
    __syncthreads();
  }
  int base = (t == 0) ? 0 : part[t - 1];
  for (int i = lo; i < hi; ++i) {
    row_ptr[i] = base;
    cursor[i] = base;
    base += cnt[i];
  }
  if (t == T - 1) row_ptr[N_NODES] = E;
}

// ---- scatter edges into dst-sorted order (node ids fit in ushort) ----
__global__ void fill_kernel(const int* __restrict__ src, const int* __restrict__ dst,
                            int* cursor, unsigned short* __restrict__ es, int E) {
  int i = blockIdx.x * blockDim.x + threadIdx.x;
  if (i < E) {
    int p = atomicAdd(&cursor[dst[i]], 1);
    es[p] = (unsigned short)src[i];
  }
}

// ---- in-place int count -> float rsqrt(max(cnt,1)) ----
__global__ void rsqrt_inplace_kernel(void* buf, int n) {
  int i = blockIdx.x * blockDim.x + threadIdx.x;
  if (i < n) {
    int c = ((const int*)buf)[i];
    ((float*)buf)[i] = rsqrtf(fmaxf((float)c, 1.0f));
  }
}

// ---- pack f32 weight [Ksrc x NOUT] into bf16 MFMA B-fragment layout ----
// frag(kb,nb): lane holds B[k=kb*32+(lane>>4)*8+e][n=nb*16+(lane&15)], e=0..7
__global__ void pack_w_kernel(const float* __restrict__ W, unsigned short* __restrict__ Bp,
                              int Ksrc, int NOUT, int k_off, int NB) {
  int idx = blockIdx.x * blockDim.x + threadIdx.x;
  if (idx >= Ksrc * NOUT) return;
  int kl = idx / NOUT, n = idx - kl * NOUT;
  int k = k_off + kl;
  int kb = k >> 5, nb = n >> 4;
  int lane = (((k >> 3) & 3) << 4) | (n & 15);
  int e = k & 7;
  Bp[(((kb * NB) + nb) * 64 + lane) * 8 + e] = f2bf(W[idx]);
}

__global__ void bias_sum_kernel(const float* a, const float* b, const float* c,
                                float* o, int n) {
  int i = blockIdx.x * blockDim.x + threadIdx.x;
  if (i < n) o[i] = a[i] + b[i] + c[i];
}

// ---- pull aggregation: one wave per node, lanes = features; writes bf16 ----
// out[d][col_off+f] = bf16( rs_in[d] * sum_e rs_out[s_e] * h[s_e][f] )
template<int D, int STR, bool BF16IN>
__global__ void gather_kernel(const void* __restrict__ hp, const int* __restrict__ row_ptr,
                              const unsigned short* __restrict__ es,
                              const float* __restrict__ rs_out, const float* __restrict__ rs_in,
                              unsigned short* __restrict__ out, int col_off) {
  int wid = (blockIdx.x * blockDim.x + threadIdx.x) >> 6;
  int lane = threadIdx.x & 63;
  if (wid >= N_NODES) return;
  int lo = row_ptr[wid], hi = row_ptr[wid + 1];
  const float* hf = (const float*)hp;
  const unsigned short* hb = (const unsigned short*)hp;
  float acc0 = 0.f, acc1 = 0.f;
  const bool two = (D > 64) && (lane < D - 64);
  int e = lo;
  for (; e + 1 < hi; e += 2) {
    int s0 = es[e], s1 = es[e + 1];
    float w0 = rs_out[s0], w1 = rs_out[s1];
    float v0 = BF16IN ? bf2f(hb[s0 * D + lane]) : hf[s0 * D + lane];
    float v1 = BF16IN ? bf2f(hb[s1 * D + lane]) : hf[s1 * D + lane];
    acc0 += w0 * v0 + w1 * v1;
    if (two) {
      float u0 = BF16IN ? bf2f(hb[s0 * D + 64 + lane]) : hf[s0 * D + 64 + lane];
      float u1 = BF16IN ? bf2f(hb[s1 * D + 64 + lane]) : hf[s1 * D + 64 + lane];
      acc1 += w0 * u0 + w1 * u1;
    }
  }
  if (e < hi) {
    int s0 = es[e];
    float w0 = rs_out[s0];
    acc0 += w0 * (BF16IN ? bf2f(hb[s0 * D + lane]) : hf[s0 * D + lane]);
    if (two) acc1 += w0 * (BF16IN ? bf2f(hb[s0 * D + 64 + lane]) : hf[s0 * D + 64 + lane]);
  }
  float ri = rs_in[wid];
  out[(long long)wid * STR + col_off + lane] = f2bf(acc0 * ri);
  if (two) out[(long long)wid * STR + col_off + 64 + lane] = f2bf(acc1 * ri);
}

// ---- MFMA GEMM: out[M x NOUT] = A[M x K](bf16) @ Bp(packed bf16) + bias ----
// wave computes 16 rows x NOUT; block = 4 waves = 64 rows; grid = M/64
template<int K, int NOUT, int OUT_BF16>
__global__ void gemm_kernel(const unsigned short* __restrict__ A,
                            const unsigned short* __restrict__ Bp,
                            const float* __restrict__ bias, void* __restrict__ outp) {
  constexpr int NB = NOUT / 16;
  constexpr int KB = K / 32;
  int wave = (blockIdx.x * blockDim.x + threadIdx.x) >> 6;
  int lane = threadIdx.x & 63;
  int row0 = wave * 16;
  int arow = row0 + (lane & 15);
  int kgrp = lane >> 4;
  f32x4 acc[NB];
#pragma unroll
  for (int i = 0; i < NB; ++i) acc[i] = (f32x4){0.f, 0.f, 0.f, 0.f};
  const short8v* ap = (const short8v*)(A + (long long)arow * K + kgrp * 8);
  const short8v* bp = (const short8v*)Bp;
#pragma unroll
  for (int kb = 0; kb < KB; ++kb) {
    short8v a = ap[kb * 4];  // k = kb*32 + kgrp*8 .. +7
#pragma unroll
    for (int nb = 0; nb < NB; ++nb) {
      short8v b = bp[(kb * NB + nb) * 64 + lane];
      acc[nb] = __builtin_amdgcn_mfma_f32_16x16x32_bf16(a, b, acc[nb], 0, 0, 0);
    }
  }
  int r0 = (lane >> 4) * 4;
  int coll = lane & 15;
#pragma unroll
  for (int nb = 0; nb < NB; ++nb) {
    int col = nb * 16 + coll;
    float bv = bias[col];
#pragma unroll
    for (int r = 0; r < 4; ++r) {
      long long row = row0 + r0 + r;
      float v = acc[nb][r] + bv;
      if (OUT_BF16) ((unsigned short*)outp)[row * NOUT + col] = f2bf(v);
      else ((float*)outp)[row * NOUT + col] = v;
    }
  }
}

// ---- batchnorm column stats: sum and sum-of-squares per feature ----
template<int D>
__global__ void bn_stats_kernel(const float* __restrict__ h, float* __restrict__ stats) {
  __shared__ float s0[D], s1[D];
  for (int i = threadIdx.x; i < D; i += blockDim.x) { s0[i] = 0.f; s1[i] = 0.f; }
  __syncthreads();
  int n = N_NODES * D;
  int stride = gridDim.x * blockDim.x;
  for (int i = blockIdx.x * blockDim.x + threadIdx.x; i < n; i += stride) {
    float v = h[i];
    int f = i % D;
    atomicAdd(&s0[f], v);
    atomicAdd(&s1[f], v * v);
  }
  __syncthreads();
  for (int i = threadIdx.x; i < D; i += blockDim.x) {
    atomicAdd(&stats[i], s0[i]);
    atomicAdd(&stats[D + i], s1[i]);
  }
}

template<int D>
__global__ void bn_finalize_kernel(const float* __restrict__ stats, const float* __restrict__ g,
                                   const float* __restrict__ be, float* scale, float* shift) {
  int f = threadIdx.x;
  if (f < D) {
    float mean = stats[f] * (1.0f / N_NODES);
    float var = stats[D + f] * (1.0f / N_NODES) - mean * mean;
    float rstd = rsqrtf(var + BN_EPS);
    float sc = g[f] * rstd;
    scale[f] = sc;
    shift[f] = be[f] - mean * sc;
  }
}

// ---- relu(h*scale+shift) -> bf16 A-matrix ----
template<int D>
__global__ void bnrelu_bf16_kernel(const float* __restrict__ h, const float* __restrict__ scale,
                                   const float* __restrict__ shift, unsigned short* __restrict__ out) {
  int i4 = blockIdx.x * blockDim.x + threadIdx.x;
  if (i4 >= N_NODES * D / 4) return;
  float4 v = ((const float4*)h)[i4];
  int f = (i4 * 4) % D;
  ushort4 o;
  o.x = f2bf(fmaxf(fmaf(v.x, scale[f + 0], shift[f + 0]), 0.f));
  o.y = f2bf(fmaxf(fmaf(v.y, scale[f + 1], shift[f + 1]), 0.f));
  o.z = f2bf(fmaxf(fmaf(v.z, scale[f + 2], shift[f + 2]), 0.f));
  o.w = f2bf(fmaxf(fmaf(v.w, scale[f + 3], shift[f + 3]), 0.f));
  ((ushort4*)out)[i4] = o;
}

extern "C" void kernel_launch(void* const* d_in, const int* in_sizes, int n_in,
                              void* d_out, int out_size, void* d_ws, size_t ws_size,
                              hipStream_t stream) {
  const int N = N_NODES;
  const float* x = (const float*)d_in[0];
  const int* src[3] = {(const int*)d_in[1], (const int*)d_in[3], (const int*)d_in[5]};
  const int* dst[3] = {(const int*)d_in[2], (const int*)d_in[4], (const int*)d_in[6]};
  const int E[3] = {in_sizes[1], in_sizes[3], in_sizes[5]};
  const int E_tot = E[0] + E[1] + E[2];

  const float* w0[3] = {(const float*)d_in[7], (const float*)d_in[9], (const float*)d_in[11]};
  const float* b0[3] = {(const float*)d_in[8], (const float*)d_in[10], (const float*)d_in[12]};
  const float* bn0_g = (const float*)d_in[13];
  const float* bn0_b = (const float*)d_in[14];
  const float* fc0_w = (const float*)d_in[15];
  const float* fc0_b = (const float*)d_in[16];
  const float* w1[3] = {(const float*)d_in[17], (const float*)d_in[19], (const float*)d_in[21]};
  const float* b1[3] = {(const float*)d_in[18], (const float*)d_in[20], (const float*)d_in[22]};
  const float* bn1_g = (const float*)d_in[23];
  const float* bn1_b = (const float*)d_in[24];
  const float* fc1_w = (const float*)d_in[25];
  const float* fc1_b = (const float*)d_in[26];

  // ---- workspace layout (~89.3 MB, under proven 93.2 MB budget) ----
  char* p = (char*)d_ws;
  auto alloc = [&](size_t bytes) { char* r = p; p += (bytes + 255) & ~255ULL; return r; };
  int* cnt = (int*)alloc((size_t)6 * N * 4);                  // -> rs floats after rsqrt
  int* row_ptr = (int*)alloc((size_t)3 * (N + 1) * 4);
  int* cursor = (int*)alloc((size_t)3 * N * 4);
  unsigned short* es = (unsigned short*)alloc((size_t)E_tot * 2);
  unsigned short* wpk = (unsigned short*)alloc((size_t)(18432 + 36864 + 9216 + 16384) * 2);
  float* b0s = (float*)alloc(96 * 4);
  float* b1s = (float*)alloc(128 * 4);
  float* stats = (float*)alloc(256 * 4);
  float* scale = (float*)alloc(128 * 4);
  float* shift = (float*)alloc(128 * 4);
  unsigned short* aggC = (unsigned short*)alloc((size_t)N * 288 * 2);
  float* hsum = (float*)alloc((size_t)N * 128 * 4);
  unsigned short* h1 = (unsigned short*)alloc((size_t)N * 96 * 2);

  unsigned short* B0p = wpk;                 // 192x96
  unsigned short* B1p = wpk + 18432;         // 288x128
  unsigned short* fc0p = wpk + 18432 + 36864;     // 96x96
  unsigned short* fc1p = wpk + 18432 + 36864 + 9216;  // 128x128
  unsigned short* A0 = aggC + (size_t)N * 192;   // 12.3MB, tail of aggC region
  unsigned short* A1 = aggC;                     // reuses aggC after GEMM1
  float* rs = (float*)cnt;

  int es_off[3] = {0, E[0], E[0] + E[1]};
  const int B = 256;

  // ---- CSR build + degrees ----
  hipMemsetAsync(cnt, 0, (size_t)6 * N * 4, stream);
  for (int e = 0; e < 3; ++e)
    count_kernel<<<cdiv(E[e], B), B, 0, stream>>>(src[e], dst[e], cnt + (2 * e) * N,
                                                  cnt + (2 * e + 1) * N, E[e]);
  for (int e = 0; e < 3; ++e)
    scan_kernel<<<1, 1024, 0, stream>>>(cnt + (2 * e + 1) * N, row_ptr + e * (N + 1),
                                        cursor + e * N, E[e]);
  for (int e = 0; e < 3; ++e)
    fill_kernel<<<cdiv(E[e], B), B, 0, stream>>>(src[e], dst[e], cursor + e * N,
                                                 es + es_off[e], E[e]);
  rsqrt_inplace_kernel<<<cdiv(6 * N, B), B, 0, stream>>>(cnt, 6 * N);

  // ---- pack weights to MFMA B-fragment layout + bias sums ----
  for (int e = 0; e < 3; ++e) {
    pack_w_kernel<<<cdiv(64 * 96, B), B, 0, stream>>>(w0[e], B0p, 64, 96, e * 64, 6);
    pack_w_kernel<<<cdiv(96 * 128, B), B, 0, stream>>>(w1[e], B1p, 96, 128, e * 96, 8);
  }
  pack_w_kernel<<<cdiv(96 * 96, B), B, 0, stream>>>(fc0_w, fc0p, 96, 96, 0, 6);
  pack_w_kernel<<<cdiv(128 * 128, B), B, 0, stream>>>(fc1_w, fc1p, 128, 128, 0, 8);
  bias_sum_kernel<<<1, 96, 0, stream>>>(b0[0], b0[1], b0[2], b0s, 96);
  bias_sum_kernel<<<1, 128, 0, stream>>>(b1[0], b1[1], b1[2], b1s, 128);

  // ---- layer 0: gather x (f32, D=64) into aggC [N][192] bf16, GEMM 192->96 ----
  for (int e = 0; e < 3; ++e)
    gather_kernel<64, 192, false><<<cdiv((long long)N * 64, B), B, 0, stream>>>(
        x, row_ptr + e * (N + 1), es + es_off[e], rs + (2 * e) * N, rs + (2 * e + 1) * N,
        aggC, e * 64);
  gemm_kernel<192, 96, 0><<<N / 64, B, 0, stream>>>(aggC, B0p, b0s, hsum);
  hipMemsetAsync(stats, 0, 2 * 96 * 4, stream);
  bn_stats_kernel<96><<<2048, B, 0, stream>>>(hsum, stats);
  bn_finalize_kernel<96><<<1, 128, 0, stream>>>(stats, bn0_g, bn0_b, scale, shift);
  bnrelu_bf16_kernel<96><<<cdiv((long long)N * 96 / 4, B), B, 0, stream>>>(hsum, scale, shift, A0);
  gemm_kernel<96, 96, 1><<<N / 64, B, 0, stream>>>(A0, fc0p, fc0_b, h1);

  // ---- layer 1: gather h1 (bf16, D=96) into aggC [N][288] bf16, GEMM 288->128 ----
  for (int e = 0; e < 3; ++e)
    gather_kernel<96, 288, true><<<cdiv((long long)N * 64, B), B, 0, stream>>>(
        h1, row_ptr + e * (N + 1), es + es_off[e], rs + (2 * e) * N, rs + (2 * e + 1) * N,
        aggC, e * 96);
  gemm_kernel<288, 128, 0><<<N / 64, B, 0, stream>>>(aggC, B1p, b1s, hsum);
  hipMemsetAsync(stats, 0, 2 * 128 * 4, stream);
  bn_stats_kernel<128><<<2048, B, 0, stream>>>(hsum, stats);
  bn_finalize_kernel<128><<<1, 128, 0, stream>>>(stats, bn1_g, bn1_b, scale, shift);
  bnrelu_bf16_kernel<128><<<cdiv((long long)N * 128 / 4, B), B, 0, stream>>>(hsum, scale, shift, A1);
  gemm_kernel<128, 128, 0><<<N / 64, B, 0, stream>>>(A1, fc1p, fc1_b, (float*)d_out);
}

// Round 4
// 857.118 us; speedup vs baseline: 13.8713x; 1.4530x over previous
//
#include <hip/hip_runtime.h>
#include <hip/hip_bf16.h>

#define N_NODES 64000
#define BN_EPS 1e-5f
#define BPT 250  // scan blocks per type = N_NODES / 256

typedef __attribute__((ext_vector_type(8))) short short8v;   // 8 bf16 (4 VGPRs)
typedef __attribute__((ext_vector_type(4))) float f32x4;

static inline int cdiv(long long a, int b) { return (int)((a + b - 1) / b); }

__device__ inline float bf2f(unsigned short u) {
  union { unsigned int i; float f; } v; v.i = ((unsigned int)u) << 16; return v.f;
}
__device__ inline unsigned short f2bf(float f) {
  __hip_bfloat16 h = __float2bfloat16(f);
  return *reinterpret_cast<unsigned short*>(&h);
}

// ---- count out/in degrees (int atomics) ----
__global__ void count_kernel(const int* __restrict__ src, const int* __restrict__ dst,
                             int* cnt_out, int* cnt_in, int E) {
  int i = blockIdx.x * blockDim.x + threadIdx.x;
  if (i < E) {
    atomicAdd(&cnt_out[src[i]], 1);
    atomicAdd(&cnt_in[dst[i]], 1);
  }
}

// ---- hierarchical scan over the 3 in-degree arrays ----
// A: per-block sums (750 blocks = 3 types x 250)
__global__ void scanA_kernel(const int* __restrict__ cnt_base, int* __restrict__ bsum) {
  int b = blockIdx.x;
  int t = b / BPT, lb = b - t * BPT;
  const int* cnt = cnt_base + (2 * t + 1) * N_NODES;
  __shared__ int s[256];
  s[threadIdx.x] = cnt[lb * 256 + threadIdx.x];
  __syncthreads();
  for (int off = 128; off > 0; off >>= 1) {
    if (threadIdx.x < off) s[threadIdx.x] += s[threadIdx.x + off];
    __syncthreads();
  }
  if (threadIdx.x == 0) bsum[b] = s[0];
}

// B: exclusive scan of each type's 250 block sums (3 blocks)
__global__ void scanB_kernel(int* __restrict__ bsum) {
  int t = blockIdx.x;
  __shared__ int s[256];
  int v = (threadIdx.x < BPT) ? bsum[t * BPT + threadIdx.x] : 0;
  s[threadIdx.x] = v;
  __syncthreads();
  for (int off = 1; off < 256; off <<= 1) {
    int add = (threadIdx.x >= off) ? s[threadIdx.x - off] : 0;
    __syncthreads();
    s[threadIdx.x] += add;
    __syncthreads();
  }
  if (threadIdx.x < BPT) bsum[t * BPT + threadIdx.x] = s[threadIdx.x] - v;
}

// C: block-local scan + block offset -> row_ptr, cursor
__global__ void scanC_kernel(const int* __restrict__ cnt_base, const int* __restrict__ bsum,
                             int* __restrict__ row_ptr, int* __restrict__ cursor) {
  int b = blockIdx.x;
  int t = b / BPT, lb = b - t * BPT;
  const int* cnt = cnt_base + (2 * t + 1) * N_NODES;
  int i = lb * 256 + threadIdx.x;
  __shared__ int s[256];
  int v = cnt[i];
  s[threadIdx.x] = v;
  __syncthreads();
  for (int off = 1; off < 256; off <<= 1) {
    int add = (threadIdx.x >= off) ? s[threadIdx.x - off] : 0;
    __syncthreads();
    s[threadIdx.x] += add;
    __syncthreads();
  }
  int excl = bsum[b] + s[threadIdx.x] - v;
  int* rp = row_ptr + t * (N_NODES + 1);
  rp[i] = excl;
  cursor[t * N_NODES + i] = excl;
  if (lb == BPT - 1 && threadIdx.x == 255) rp[N_NODES] = excl + v;
}

// ---- scatter edges into dst-sorted order (node ids fit in ushort) ----
__global__ void fill_kernel(const int* __restrict__ src, const int* __restrict__ dst,
                            int* cursor, unsigned short* __restrict__ es, int E) {
  int i = blockIdx.x * blockDim.x + threadIdx.x;
  if (i < E) {
    int p = atomicAdd(&cursor[dst[i]], 1);
    es[p] = (unsigned short)src[i];
  }
}

// ---- in-place int count -> float rsqrt(max(cnt,1)) ----
__global__ void rsqrt_inplace_kernel(void* buf, int n) {
  int i = blockIdx.x * blockDim.x + threadIdx.x;
  if (i < n) {
    int c = ((const int*)buf)[i];
    ((float*)buf)[i] = rsqrtf(fmaxf((float)c, 1.0f));
  }
}

// ---- pack f32 weight [Ksrc x NOUT] into bf16 MFMA B-fragment layout ----
// frag(kb,nb): lane holds B[k=kb*32+(lane>>4)*8+e][n=nb*16+(lane&15)], e=0..7
__global__ void pack_w_kernel(const float* __restrict__ W, unsigned short* __restrict__ Bp,
                              int Ksrc, int NOUT, int k_off, int NB) {
  int idx = blockIdx.x * blockDim.x + threadIdx.x;
  if (idx >= Ksrc * NOUT) return;
  int kl = idx / NOUT, n = idx - kl * NOUT;
  int k = k_off + kl;
  int kb = k >> 5, nb = n >> 4;
  int lane = (((k >> 3) & 3) << 4) | (n & 15);
  int e = k & 7;
  Bp[(((kb * NB) + nb) * 64 + lane) * 8 + e] = f2bf(W[idx]);
}

__global__ void bias_sum_kernel(const float* a, const float* b, const float* c,
                                float* o, int n) {
  int i = blockIdx.x * blockDim.x + threadIdx.x;
  if (i < n) o[i] = a[i] + b[i] + c[i];
}

// ---- pull aggregation: one wave per node, lanes = features; writes bf16 ----
template<int D, int STR, bool BF16IN>
__global__ void gather_kernel(const void* __restrict__ hp, const int* __restrict__ row_ptr,
                              const unsigned short* __restrict__ es,
                              const float* __restrict__ rs_out, const float* __restrict__ rs_in,
                              unsigned short* __restrict__ out, int col_off) {
  int wid = (blockIdx.x * blockDim.x + threadIdx.x) >> 6;
  int lane = threadIdx.x & 63;
  if (wid >= N_NODES) return;
  int lo = row_ptr[wid], hi = row_ptr[wid + 1];
  const float* hf = (const float*)hp;
  const unsigned short* hb = (const unsigned short*)hp;
  float acc0 = 0.f, acc1 = 0.f;
  const bool two = (D > 64) && (lane < D - 64);
  int e = lo;
  for (; e + 1 < hi; e += 2) {
    int s0 = es[e], s1 = es[e + 1];
    float w0 = rs_out[s0], w1 = rs_out[s1];
    float v0 = BF16IN ? bf2f(hb[s0 * D + lane]) : hf[s0 * D + lane];
    float v1 = BF16IN ? bf2f(hb[s1 * D + lane]) : hf[s1 * D + lane];
    acc0 += w0 * v0 + w1 * v1;
    if (two) {
      float u0 = BF16IN ? bf2f(hb[s0 * D + 64 + lane]) : hf[s0 * D + 64 + lane];
      float u1 = BF16IN ? bf2f(hb[s1 * D + 64 + lane]) : hf[s1 * D + 64 + lane];
      acc1 += w0 * u0 + w1 * u1;
    }
  }
  if (e < hi) {
    int s0 = es[e];
    float w0 = rs_out[s0];
    acc0 += w0 * (BF16IN ? bf2f(hb[s0 * D + lane]) : hf[s0 * D + lane]);
    if (two) acc1 += w0 * (BF16IN ? bf2f(hb[s0 * D + 64 + lane]) : hf[s0 * D + 64 + lane]);
  }
  float ri = rs_in[wid];
  out[(long long)wid * STR + col_off + lane] = f2bf(acc0 * ri);
  if (two) out[(long long)wid * STR + col_off + 64 + lane] = f2bf(acc1 * ri);
}

// ---- MFMA GEMM: out[M x NOUT] = A[M x K](bf16) @ Bp(packed bf16) + bias ----
template<int K, int NOUT, int OUT_BF16>
__global__ void gemm_kernel(const unsigned short* __restrict__ A,
                            const unsigned short* __restrict__ Bp,
                            const float* __restrict__ bias, void* __restrict__ outp) {
  constexpr int NB = NOUT / 16;
  constexpr int KB = K / 32;
  int wave = (blockIdx.x * blockDim.x + threadIdx.x) >> 6;
  int lane = threadIdx.x & 63;
  int row0 = wave * 16;
  int arow = row0 + (lane & 15);
  int kgrp = lane >> 4;
  f32x4 acc[NB];
#pragma unroll
  for (int i = 0; i < NB; ++i) acc[i] = (f32x4){0.f, 0.f, 0.f, 0.f};
  const short8v* ap = (const short8v*)(A + (long long)arow * K + kgrp * 8);
  const short8v* bp = (const short8v*)Bp;
#pragma unroll
  for (int kb = 0; kb < KB; ++kb) {
    short8v a = ap[kb * 4];
#pragma unroll
    for (int nb = 0; nb < NB; ++nb) {
      short8v b = bp[(kb * NB + nb) * 64 + lane];
      acc[nb] = __builtin_amdgcn_mfma_f32_16x16x32_bf16(a, b, acc[nb], 0, 0, 0);
    }
  }
  int r0 = (lane >> 4) * 4;
  int coll = lane & 15;
#pragma unroll
  for (int nb = 0; nb < NB; ++nb) {
    int col = nb * 16 + coll;
    float bv = bias[col];
#pragma unroll
    for (int r = 0; r < 4; ++r) {
      long long row = row0 + r0 + r;
      float v = acc[nb][r] + bv;
      if (OUT_BF16) ((unsigned short*)outp)[row * NOUT + col] = f2bf(v);
      else ((float*)outp)[row * NOUT + col] = v;
    }
  }
}

// ---- batchnorm column stats: sum and sum-of-squares per feature ----
template<int D>
__global__ void bn_stats_kernel(const float* __restrict__ h, float* __restrict__ stats) {
  __shared__ float s0[D], s1[D];
  for (int i = threadIdx.x; i < D; i += blockDim.x) { s0[i] = 0.f; s1[i] = 0.f; }
  __syncthreads();
  int n = N_NODES * D;
  int stride = gridDim.x * blockDim.x;
  for (int i = blockIdx.x * blockDim.x + threadIdx.x; i < n; i += stride) {
    float v = h[i];
    int f = i % D;
    atomicAdd(&s0[f], v);
    atomicAdd(&s1[f], v * v);
  }
  __syncthreads();
  for (int i = threadIdx.x; i < D; i += blockDim.x) {
    atomicAdd(&stats[i], s0[i]);
    atomicAdd(&stats[D + i], s1[i]);
  }
}

template<int D>
__global__ void bn_finalize_kernel(const float* __restrict__ stats, const float* __restrict__ g,
                                   const float* __restrict__ be, float* scale, float* shift) {
  int f = threadIdx.x;
  if (f < D) {
    float mean = stats[f] * (1.0f / N_NODES);
    float var = stats[D + f] * (1.0f / N_NODES) - mean * mean;
    float rstd = rsqrtf(var + BN_EPS);
    float sc = g[f] * rstd;
    scale[f] = sc;
    shift[f] = be[f] - mean * sc;
  }
}

// ---- relu(h*scale+shift) -> bf16 A-matrix ----
template<int D>
__global__ void bnrelu_bf16_kernel(const float* __restrict__ h, const float* __restrict__ scale,
                                   const float* __restrict__ shift, unsigned short* __restrict__ out) {
  int i4 = blockIdx.x * blockDim.x + threadIdx.x;
  if (i4 >= N_NODES * D / 4) return;
  float4 v = ((const float4*)h)[i4];
  int f = (i4 * 4) % D;
  ushort4 o;
  o.x = f2bf(fmaxf(fmaf(v.x, scale[f + 0], shift[f + 0]), 0.f));
  o.y = f2bf(fmaxf(fmaf(v.y, scale[f + 1], shift[f + 1]), 0.f));
  o.z = f2bf(fmaxf(fmaf(v.z, scale[f + 2], shift[f + 2]), 0.f));
  o.w = f2bf(fmaxf(fmaf(v.w, scale[f + 3], shift[f + 3]), 0.f));
  ((ushort4*)out)[i4] = o;
}

extern "C" void kernel_launch(void* const* d_in, const int* in_sizes, int n_in,
                              void* d_out, int out_size, void* d_ws, size_t ws_size,
                              hipStream_t stream) {
  const int N = N_NODES;
  const float* x = (const float*)d_in[0];
  const int* src[3] = {(const int*)d_in[1], (const int*)d_in[3], (const int*)d_in[5]};
  const int* dst[3] = {(const int*)d_in[2], (const int*)d_in[4], (const int*)d_in[6]};
  const int E[3] = {in_sizes[1], in_sizes[3], in_sizes[5]};
  const int E_tot = E[0] + E[1] + E[2];

  const float* w0[3] = {(const float*)d_in[7], (const float*)d_in[9], (const float*)d_in[11]};
  const float* b0[3] = {(const float*)d_in[8], (const float*)d_in[10], (const float*)d_in[12]};
  const float* bn0_g = (const float*)d_in[13];
  const float* bn0_b = (const float*)d_in[14];
  const float* fc0_w = (const float*)d_in[15];
  const float* fc0_b = (const float*)d_in[16];
  const float* w1[3] = {(const float*)d_in[17], (const float*)d_in[19], (const float*)d_in[21]};
  const float* b1[3] = {(const float*)d_in[18], (const float*)d_in[20], (const float*)d_in[22]};
  const float* bn1_g = (const float*)d_in[23];
  const float* bn1_b = (const float*)d_in[24];
  const float* fc1_w = (const float*)d_in[25];
  const float* fc1_b = (const float*)d_in[26];

  // ---- workspace layout (~89.3 MB) ----
  char* p = (char*)d_ws;
  auto alloc = [&](size_t bytes) { char* r = p; p += (bytes + 255) & ~255ULL; return r; };
  int* cnt = (int*)alloc((size_t)6 * N * 4);                  // -> rs floats after rsqrt
  int* row_ptr = (int*)alloc((size_t)3 * (N + 1) * 4);
  int* cursor = (int*)alloc((size_t)3 * N * 4);
  int* bsum = (int*)alloc((size_t)3 * BPT * 4);
  unsigned short* es = (unsigned short*)alloc((size_t)E_tot * 2);
  unsigned short* wpk = (unsigned short*)alloc((size_t)(18432 + 36864 + 9216 + 16384) * 2);
  float* b0s = (float*)alloc(96 * 4);
  float* b1s = (float*)alloc(128 * 4);
  float* stats = (float*)alloc(256 * 4);
  float* scale = (float*)alloc(128 * 4);
  float* shift = (float*)alloc(128 * 4);
  unsigned short* aggC = (unsigned short*)alloc((size_t)N * 288 * 2);
  float* hsum = (float*)alloc((size_t)N * 128 * 4);
  unsigned short* h1 = (unsigned short*)alloc((size_t)N * 96 * 2);

  unsigned short* B0p = wpk;                 // 192x96
  unsigned short* B1p = wpk + 18432;         // 288x128
  unsigned short* fc0p = wpk + 18432 + 36864;     // 96x96
  unsigned short* fc1p = wpk + 18432 + 36864 + 9216;  // 128x128
  unsigned short* A0 = aggC + (size_t)N * 192;   // tail of aggC region
  unsigned short* A1 = aggC;                     // reuses aggC after GEMM1
  float* rs = (float*)cnt;

  int es_off[3] = {0, E[0], E[0] + E[1]};
  const int B = 256;

  // ---- CSR build + degrees ----
  hipMemsetAsync(cnt, 0, (size_t)6 * N * 4, stream);
  for (int e = 0; e < 3; ++e)
    count_kernel<<<cdiv(E[e], B), B, 0, stream>>>(src[e], dst[e], cnt + (2 * e) * N,
                                                  cnt + (2 * e + 1) * N, E[e]);
  scanA_kernel<<<3 * BPT, 256, 0, stream>>>(cnt, bsum);
  scanB_kernel<<<3, 256, 0, stream>>>(bsum);
  scanC_kernel<<<3 * BPT, 256, 0, stream>>>(cnt, bsum, row_ptr, cursor);
  for (int e = 0; e < 3; ++e)
    fill_kernel<<<cdiv(E[e], B), B, 0, stream>>>(src[e], dst[e], cursor + e * N,
                                                 es + es_off[e], E[e]);
  rsqrt_inplace_kernel<<<cdiv(6 * N, B), B, 0, stream>>>(cnt, 6 * N);

  // ---- pack weights to MFMA B-fragment layout + bias sums ----
  for (int e = 0; e < 3; ++e) {
    pack_w_kernel<<<cdiv(64 * 96, B), B, 0, stream>>>(w0[e], B0p, 64, 96, e * 64, 6);
    pack_w_kernel<<<cdiv(96 * 128, B), B, 0, stream>>>(w1[e], B1p, 96, 128, e * 96, 8);
  }
  pack_w_kernel<<<cdiv(96 * 96, B), B, 0, stream>>>(fc0_w, fc0p, 96, 96, 0, 6);
  pack_w_kernel<<<cdiv(128 * 128, B), B, 0, stream>>>(fc1_w, fc1p, 128, 128, 0, 8);
  bias_sum_kernel<<<1, 96, 0, stream>>>(b0[0], b0[1], b0[2], b0s, 96);
  bias_sum_kernel<<<1, 128, 0, stream>>>(b1[0], b1[1], b1[2], b1s, 128);

  // ---- layer 0: gather x (f32, D=64) into aggC [N][192] bf16, GEMM 192->96 ----
  for (int e = 0; e < 3; ++e)
    gather_kernel<64, 192, false><<<cdiv((long long)N * 64, B), B, 0, stream>>>(
        x, row_ptr + e * (N + 1), es + es_off[e], rs + (2 * e) * N, rs + (2 * e + 1) * N,
        aggC, e * 64);
  gemm_kernel<192, 96, 0><<<N / 64, B, 0, stream>>>(aggC, B0p, b0s, hsum);
  hipMemsetAsync(stats, 0, 2 * 96 * 4, stream);
  bn_stats_kernel<96><<<2048, B, 0, stream>>>(hsum, stats);
  bn_finalize_kernel<96><<<1, 128, 0, stream>>>(stats, bn0_g, bn0_b, scale, shift);
  bnrelu_bf16_kernel<96><<<cdiv((long long)N * 96 / 4, B), B, 0, stream>>>(hsum, scale, shift, A0);
  gemm_kernel<96, 96, 1><<<N / 64, B, 0, stream>>>(A0, fc0p, fc0_b, h1);

  // ---- layer 1: gather h1 (bf16, D=96) into aggC [N][288] bf16, GEMM 288->128 ----
  for (int e = 0; e < 3; ++e)
    gather_kernel<96, 288, true><<<cdiv((long long)N * 64, B), B, 0, stream>>>(
        h1, row_ptr + e * (N + 1), es + es_off[e], rs + (2 * e) * N, rs + (2 * e + 1) * N,
        aggC, e * 96);
  gemm_kernel<288, 128, 0><<<N / 64, B, 0, stream>>>(aggC, B1p, b1s, hsum);
  hipMemsetAsync(stats, 0, 2 * 128 * 4, stream);
  bn_stats_kernel<128><<<2048, B, 0, stream>>>(hsum, stats);
  bn_finalize_kernel<128><<<1, 128, 0, stream>>>(stats, bn1_g, bn1_b, scale, shift);
  bnrelu_bf16_kernel<128><<<cdiv((long long)N * 128 / 4, B), B, 0, stream>>>(hsum, scale, shift, A1);
  gemm_kernel<128, 128, 0><<<N / 64, B, 0, stream>>>(A1, fc1p, fc1_b, (float*)d_out);
}

// Round 5
// 663.938 us; speedup vs baseline: 17.9073x; 1.2910x over previous
//
#include <hip/hip_runtime.h>
#include <hip/hip_bf16.h>

#define N_NODES 64000
#define BN_EPS 1e-5f
#define NBL 512      // radix blocks per type
#define NBKT 250     // coarse buckets = N_NODES / 256

typedef __attribute__((ext_vector_type(8))) short short8v;   // 8 bf16 (4 VGPRs)
typedef __attribute__((ext_vector_type(4))) float f32x4;

static inline int cdiv(long long a, int b) { return (int)((a + b - 1) / b); }

__device__ inline float bf2f(unsigned short u) {
  union { unsigned int i; float f; } v; v.i = ((unsigned int)u) << 16; return v.f;
}
__device__ inline unsigned short f2bf(float f) {
  __hip_bfloat16 h = __float2bfloat16(f);
  return *reinterpret_cast<unsigned short*>(&h);
}

// ================= atomic-free CSR build (two-level radix) =================
// R1: per-(type,block) LDS histogram of key>>8  -> Hist[(t*NBL+blk)*256+bin]
__global__ void r1_hist_kernel(const int* __restrict__ k0, const int* __restrict__ k1,
                               const int* __restrict__ k2, int E0, int E1, int E2,
                               int* __restrict__ Hist) {
  int t = blockIdx.x / NBL, blk = blockIdx.x - t * NBL;
  const int* key = t == 0 ? k0 : (t == 1 ? k1 : k2);
  int E = t == 0 ? E0 : (t == 1 ? E1 : E2);
  __shared__ int h[256];
  h[threadIdx.x] = 0;
  __syncthreads();
  int ch = (E + NBL - 1) / NBL;
  int lo = blk * ch, hi = min(lo + ch, E);
  for (int i = lo + threadIdx.x; i < hi; i += 256) atomicAdd(&h[key[i] >> 8], 1);
  __syncthreads();
  Hist[(t * NBL + blk) * 256 + threadIdx.x] = h[threadIdx.x];
}

// R2: per-type: convert Hist to absolute scatter offsets; write bucket bases
__global__ void r2_scan_kernel(int* __restrict__ Hist, int* __restrict__ bbase,
                               int E0, int E1, int E2) {
  int t = blockIdx.x;
  int bin = threadIdx.x;
  int* H = Hist + (size_t)t * NBL * 256;
  int total = 0;
  for (int blk = 0; blk < NBL; ++blk) total += H[blk * 256 + bin];
  __shared__ int s[256];
  s[bin] = total;
  __syncthreads();
  for (int o = 1; o < 256; o <<= 1) {
    int a = (bin >= o) ? s[bin - o] : 0;
    __syncthreads();
    s[bin] += a;
    __syncthreads();
  }
  int base = s[bin] - total;  // exclusive scan across bins
  if (bin <= NBKT) bbase[t * (NBKT + 1) + bin] = base;
  int run = base;
  for (int blk = 0; blk < NBL; ++blk) {
    int v = H[blk * 256 + bin];
    H[blk * 256 + bin] = run;
    run += v;
  }
}

// R3: scatter (dst&255, src) into bucket-segmented tmp at precomputed offsets
__global__ void r3_scatter_kernel(const int* __restrict__ d0, const int* __restrict__ d1,
                                  const int* __restrict__ d2, const int* __restrict__ s0,
                                  const int* __restrict__ s1, const int* __restrict__ s2,
                                  int E0, int E1, int E2, const int* __restrict__ Hist,
                                  unsigned int* __restrict__ tmp) {
  int t = blockIdx.x / NBL, blk = blockIdx.x - t * NBL;
  const int* dst = t == 0 ? d0 : (t == 1 ? d1 : d2);
  const int* src = t == 0 ? s0 : (t == 1 ? s1 : s2);
  int E = t == 0 ? E0 : (t == 1 ? E1 : E2);
  unsigned int* tp = tmp + (t == 0 ? 0 : (t == 1 ? E0 : E0 + E1));
  __shared__ int off[256];
  off[threadIdx.x] = Hist[(t * NBL + blk) * 256 + threadIdx.x];
  __syncthreads();
  int ch = (E + NBL - 1) / NBL;
  int lo = blk * ch, hi = min(lo + ch, E);
  for (int i = lo + threadIdx.x; i < hi; i += 256) {
    int d = dst[i];
    int p = atomicAdd(&off[d >> 8], 1);
    tp[p] = ((unsigned)(d & 255) << 16) | (unsigned)src[i];
  }
}

// R4: per bucket: fine counting sort -> es, row_ptr, cnt_in
__global__ void r4_bucket_kernel(const unsigned int* __restrict__ tmp,
                                 const int* __restrict__ bbase, int E0, int E1, int E2,
                                 unsigned short* __restrict__ es, int* __restrict__ row_ptr,
                                 int* __restrict__ cnt) {
  int t = blockIdx.x / NBKT, b = blockIdx.x - t * NBKT;
  const int* bb = bbase + t * (NBKT + 1);
  int teo = (t == 0 ? 0 : (t == 1 ? E0 : E0 + E1));
  int E = t == 0 ? E0 : (t == 1 ? E1 : E2);
  const unsigned int* tp = tmp + teo;
  unsigned short* esp = es + teo;
  int lo = bb[b], hi = bb[b + 1];
  __shared__ int c[256], s[256];
  c[threadIdx.x] = 0;
  __syncthreads();
  for (int i = lo + threadIdx.x; i < hi; i += 256) atomicAdd(&c[tp[i] >> 16], 1);
  __syncthreads();
  int v = c[threadIdx.x];
  s[threadIdx.x] = v;
  __syncthreads();
  for (int o = 1; o < 256; o <<= 1) {
    int a = (threadIdx.x >= o) ? s[threadIdx.x - o] : 0;
    __syncthreads();
    s[threadIdx.x] += a;
    __syncthreads();
  }
  int excl = s[threadIdx.x] - v;
  int node = b * 256 + threadIdx.x;
  cnt[(2 * t + 1) * N_NODES + node] = v;
  row_ptr[t * (N_NODES + 1) + node] = lo + excl;
  if (b == NBKT - 1 && threadIdx.x == 255) row_ptr[t * (N_NODES + 1) + N_NODES] = E;
  __syncthreads();
  s[threadIdx.x] = lo + excl;  // repurpose as cursor
  __syncthreads();
  for (int i = lo + threadIdx.x; i < hi; i += 256) {
    unsigned int w = tp[i];
    int p = atomicAdd(&s[w >> 16], 1);
    esp[p] = (unsigned short)(w & 0xFFFF);
  }
}

// R3b: scatter src fine-byte only (for out-degree counting)
__global__ void r3b_scatter_kernel(const int* __restrict__ s0, const int* __restrict__ s1,
                                   const int* __restrict__ s2, int E0, int E1, int E2,
                                   const int* __restrict__ Hist, unsigned char* __restrict__ tmp8) {
  int t = blockIdx.x / NBL, blk = blockIdx.x - t * NBL;
  const int* src = t == 0 ? s0 : (t == 1 ? s1 : s2);
  int E = t == 0 ? E0 : (t == 1 ? E1 : E2);
  unsigned char* tp = tmp8 + (t == 0 ? 0 : (t == 1 ? E0 : E0 + E1));
  __shared__ int off[256];
  off[threadIdx.x] = Hist[(t * NBL + blk) * 256 + threadIdx.x];
  __syncthreads();
  int ch = (E + NBL - 1) / NBL;
  int lo = blk * ch, hi = min(lo + ch, E);
  for (int i = lo + threadIdx.x; i < hi; i += 256) {
    int sv = src[i];
    int p = atomicAdd(&off[sv >> 8], 1);
    tp[p] = (unsigned char)(sv & 255);
  }
}

// R4b: per bucket fine counts -> cnt_out
__global__ void r4b_bucket_kernel(const unsigned char* __restrict__ tmp8,
                                  const int* __restrict__ bbase, int E0, int E1, int E2,
                                  int* __restrict__ cnt) {
  int t = blockIdx.x / NBKT, b = blockIdx.x - t * NBKT;
  const int* bb = bbase + t * (NBKT + 1);
  const unsigned char* tp = tmp8 + (t == 0 ? 0 : (t == 1 ? E0 : E0 + E1));
  int lo = bb[b], hi = bb[b + 1];
  __shared__ int c[256];
  c[threadIdx.x] = 0;
  __syncthreads();
  for (int i = lo + threadIdx.x; i < hi; i += 256) atomicAdd(&c[tp[i]], 1);
  __syncthreads();
  int node = b * 256 + threadIdx.x;
  cnt[(2 * t) * N_NODES + node] = c[threadIdx.x];
}

// ---- in-place int count -> float rsqrt(max(cnt,1)) ----
__global__ void rsqrt_inplace_kernel(void* buf, int n) {
  int i = blockIdx.x * blockDim.x + threadIdx.x;
  if (i < n) {
    int c = ((const int*)buf)[i];
    ((float*)buf)[i] = rsqrtf(fmaxf((float)c, 1.0f));
  }
}

// ---- f32 -> bf16 bulk convert ----
__global__ void f32_to_bf16_kernel(const float* __restrict__ in, unsigned short* __restrict__ out,
                                   int n4) {
  int i = blockIdx.x * blockDim.x + threadIdx.x;
  if (i < n4) {
    float4 v = ((const float4*)in)[i];
    ushort4 o;
    o.x = f2bf(v.x); o.y = f2bf(v.y); o.z = f2bf(v.z); o.w = f2bf(v.w);
    ((ushort4*)out)[i] = o;
  }
}

// ---- pack f32 weight [Ksrc x NOUT] into bf16 MFMA B-fragment layout ----
__global__ void pack_w_kernel(const float* __restrict__ W, unsigned short* __restrict__ Bp,
                              int Ksrc, int NOUT, int k_off, int NB) {
  int idx = blockIdx.x * blockDim.x + threadIdx.x;
  if (idx >= Ksrc * NOUT) return;
  int kl = idx / NOUT, n = idx - kl * NOUT;
  int k = k_off + kl;
  int kb = k >> 5, nb = n >> 4;
  int lane = (((k >> 3) & 3) << 4) | (n & 15);
  int e = k & 7;
  Bp[(((kb * NB) + nb) * 64 + lane) * 8 + e] = f2bf(W[idx]);
}

__global__ void bias_sum_kernel(const float* a, const float* b, const float* c,
                                float* o, int n) {
  int i = blockIdx.x * blockDim.x + threadIdx.x;
  if (i < n) o[i] = a[i] + b[i] + c[i];
}

// ---- pull aggregation: one wave per node, lanes = features; writes bf16 ----
template<int D, int STR>
__global__ void gather_kernel(const unsigned short* __restrict__ hb,
                              const int* __restrict__ row_ptr,
                              const unsigned short* __restrict__ es,
                              const float* __restrict__ rs_out, const float* __restrict__ rs_in,
                              unsigned short* __restrict__ out, int col_off) {
  int wid = (blockIdx.x * blockDim.x + threadIdx.x) >> 6;
  int lane = threadIdx.x & 63;
  if (wid >= N_NODES) return;
  int lo = row_ptr[wid], hi = row_ptr[wid + 1];
  float acc0 = 0.f, acc1 = 0.f;
  const bool two = (D > 64) && (lane < D - 64);
  int e = lo;
  for (; e + 1 < hi; e += 2) {
    int s0 = es[e], s1 = es[e + 1];
    float w0 = rs_out[s0], w1 = rs_out[s1];
    acc0 += w0 * bf2f(hb[s0 * D + lane]) + w1 * bf2f(hb[s1 * D + lane]);
    if (two) acc1 += w0 * bf2f(hb[s0 * D + 64 + lane]) + w1 * bf2f(hb[s1 * D + 64 + lane]);
  }
  if (e < hi) {
    int s0 = es[e];
    float w0 = rs_out[s0];
    acc0 += w0 * bf2f(hb[s0 * D + lane]);
    if (two) acc1 += w0 * bf2f(hb[s0 * D + 64 + lane]);
  }
  float ri = rs_in[wid];
  out[(long long)wid * STR + col_off + lane] = f2bf(acc0 * ri);
  if (two) out[(long long)wid * STR + col_off + 64 + lane] = f2bf(acc1 * ri);
}

// ---- MFMA GEMM: out[M x NOUT] = A[M x K](bf16) @ Bp(packed bf16) + bias ----
template<int K, int NOUT, int OUT_BF16>
__global__ void gemm_kernel(const unsigned short* __restrict__ A,
                            const unsigned short* __restrict__ Bp,
                            const float* __restrict__ bias, void* __restrict__ outp) {
  constexpr int NB = NOUT / 16;
  constexpr int KB = K / 32;
  int wave = (blockIdx.x * blockDim.x + threadIdx.x) >> 6;
  int lane = threadIdx.x & 63;
  int row0 = wave * 16;
  int arow = row0 + (lane & 15);
  int kgrp = lane >> 4;
  f32x4 acc[NB];
#pragma unroll
  for (int i = 0; i < NB; ++i) acc[i] = (f32x4){0.f, 0.f, 0.f, 0.f};
  const short8v* ap = (const short8v*)(A + (long long)arow * K + kgrp * 8);
  const short8v* bp = (const short8v*)Bp;
#pragma unroll
  for (int kb = 0; kb < KB; ++kb) {
    short8v a = ap[kb * 4];
#pragma unroll
    for (int nb = 0; nb < NB; ++nb) {
      short8v b = bp[(kb * NB + nb) * 64 + lane];
      acc[nb] = __builtin_amdgcn_mfma_f32_16x16x32_bf16(a, b, acc[nb], 0, 0, 0);
    }
  }
  int r0 = (lane >> 4) * 4;
  int coll = lane & 15;
#pragma unroll
  for (int nb = 0; nb < NB; ++nb) {
    int col = nb * 16 + coll;
    float bv = bias[col];
#pragma unroll
    for (int r = 0; r < 4; ++r) {
      long long row = row0 + r0 + r;
      float v = acc[nb][r] + bv;
      if (OUT_BF16) ((unsigned short*)outp)[row * NOUT + col] = f2bf(v);
      else ((float*)outp)[row * NOUT + col] = v;
    }
  }
}

// ---- batchnorm column stats: sum and sum-of-squares per feature ----
template<int D>
__global__ void bn_stats_kernel(const float* __restrict__ h, float* __restrict__ stats) {
  __shared__ float s0[D], s1[D];
  for (int i = threadIdx.x; i < D; i += blockDim.x) { s0[i] = 0.f; s1[i] = 0.f; }
  __syncthreads();
  int n = N_NODES * D;
  int stride = gridDim.x * blockDim.x;
  for (int i = blockIdx.x * blockDim.x + threadIdx.x; i < n; i += stride) {
    float v = h[i];
    int f = i % D;
    atomicAdd(&s0[f], v);
    atomicAdd(&s1[f], v * v);
  }
  __syncthreads();
  for (int i = threadIdx.x; i < D; i += blockDim.x) {
    atomicAdd(&stats[i], s0[i]);
    atomicAdd(&stats[D + i], s1[i]);
  }
}

template<int D>
__global__ void bn_finalize_kernel(const float* __restrict__ stats, const float* __restrict__ g,
                                   const float* __restrict__ be, float* scale, float* shift) {
  int f = threadIdx.x;
  if (f < D) {
    float mean = stats[f] * (1.0f / N_NODES);
    float var = stats[D + f] * (1.0f / N_NODES) - mean * mean;
    float rstd = rsqrtf(var + BN_EPS);
    float sc = g[f] * rstd;
    scale[f] = sc;
    shift[f] = be[f] - mean * sc;
  }
}

// ---- relu(h*scale+shift) -> bf16 A-matrix ----
template<int D>
__global__ void bnrelu_bf16_kernel(const float* __restrict__ h, const float* __restrict__ scale,
                                   const float* __restrict__ shift, unsigned short* __restrict__ out) {
  int i4 = blockIdx.x * blockDim.x + threadIdx.x;
  if (i4 >= N_NODES * D / 4) return;
  float4 v = ((const float4*)h)[i4];
  int f = (i4 * 4) % D;
  ushort4 o;
  o.x = f2bf(fmaxf(fmaf(v.x, scale[f + 0], shift[f + 0]), 0.f));
  o.y = f2bf(fmaxf(fmaf(v.y, scale[f + 1], shift[f + 1]), 0.f));
  o.z = f2bf(fmaxf(fmaf(v.z, scale[f + 2], shift[f + 2]), 0.f));
  o.w = f2bf(fmaxf(fmaf(v.w, scale[f + 3], shift[f + 3]), 0.f));
  ((ushort4*)out)[i4] = o;
}

extern "C" void kernel_launch(void* const* d_in, const int* in_sizes, int n_in,
                              void* d_out, int out_size, void* d_ws, size_t ws_size,
                              hipStream_t stream) {
  const int N = N_NODES;
  const float* x = (const float*)d_in[0];
  const int* src[3] = {(const int*)d_in[1], (const int*)d_in[3], (const int*)d_in[5]};
  const int* dst[3] = {(const int*)d_in[2], (const int*)d_in[4], (const int*)d_in[6]};
  const int E[3] = {in_sizes[1], in_sizes[3], in_sizes[5]};
  const int E_tot = E[0] + E[1] + E[2];

  const float* w0[3] = {(const float*)d_in[7], (const float*)d_in[9], (const float*)d_in[11]};
  const float* b0[3] = {(const float*)d_in[8], (const float*)d_in[10], (const float*)d_in[12]};
  const float* bn0_g = (const float*)d_in[13];
  const float* bn0_b = (const float*)d_in[14];
  const float* fc0_w = (const float*)d_in[15];
  const float* fc0_b = (const float*)d_in[16];
  const float* w1[3] = {(const float*)d_in[17], (const float*)d_in[19], (const float*)d_in[21]};
  const float* b1[3] = {(const float*)d_in[18], (const float*)d_in[20], (const float*)d_in[22]};
  const float* bn1_g = (const float*)d_in[23];
  const float* bn1_b = (const float*)d_in[24];
  const float* fc1_w = (const float*)d_in[25];
  const float* fc1_b = (const float*)d_in[26];

  // ---- workspace layout (~88.5 MB) ----
  char* p = (char*)d_ws;
  auto alloc = [&](size_t bytes) { char* r = p; p += (bytes + 255) & ~255ULL; return r; };
  int* cnt = (int*)alloc((size_t)6 * N * 4);                  // -> rs floats after rsqrt
  int* row_ptr = (int*)alloc((size_t)3 * (N + 1) * 4);
  int* bbase = (int*)alloc((size_t)3 * (NBKT + 1) * 4);
  unsigned short* es = (unsigned short*)alloc((size_t)E_tot * 2);
  unsigned short* wpk = (unsigned short*)alloc((size_t)(18432 + 36864 + 9216 + 16384) * 2);
  float* b0s = (float*)alloc(96 * 4);
  float* b1s = (float*)alloc(128 * 4);
  float* stats = (float*)alloc(256 * 4);
  float* scale = (float*)alloc(128 * 4);
  float* shift = (float*)alloc(128 * 4);
  unsigned short* aggC = (unsigned short*)alloc((size_t)N * 288 * 2);
  float* hsum = (float*)alloc((size_t)N * 128 * 4);            // also hosts tmp/Hist/xb early
  unsigned short* h1 = (unsigned short*)alloc((size_t)N * 96 * 2);

  unsigned short* B0p = wpk;                          // 192x96
  unsigned short* B1p = wpk + 18432;                  // 288x128
  unsigned short* fc0p = wpk + 18432 + 36864;         // 96x96
  unsigned short* fc1p = wpk + 18432 + 36864 + 9216;  // 128x128
  unsigned short* A0 = aggC + (size_t)N * 192;        // tail of aggC region
  unsigned short* A1 = aggC;                          // reuses aggC after GEMM1
  float* rs = (float*)cnt;

  // transient aliases inside hsum region (all dead before gemm0 writes hsum)
  unsigned int* tmp = (unsigned int*)hsum;                        // E_tot*4 <= 8.2MB
  unsigned char* tmp8 = (unsigned char*)hsum;                     // E_tot   <= 2.1MB
  int* Hist = (int*)((char*)hsum + ((size_t)9 << 20));            // 1.57MB
  unsigned short* xb = (unsigned short*)hsum;                     // 8.2MB (after tmp dead)

  const int B = 256;

  // ---- CSR build (dst sort) + cnt_in ----
  r1_hist_kernel<<<3 * NBL, 256, 0, stream>>>(dst[0], dst[1], dst[2], E[0], E[1], E[2], Hist);
  r2_scan_kernel<<<3, 256, 0, stream>>>(Hist, bbase, E[0], E[1], E[2]);
  r3_scatter_kernel<<<3 * NBL, 256, 0, stream>>>(dst[0], dst[1], dst[2], src[0], src[1], src[2],
                                                 E[0], E[1], E[2], Hist, tmp);
  r4_bucket_kernel<<<3 * NBKT, 256, 0, stream>>>(tmp, bbase, E[0], E[1], E[2], es, row_ptr, cnt);
  // ---- out-degree counts (src) ----
  r1_hist_kernel<<<3 * NBL, 256, 0, stream>>>(src[0], src[1], src[2], E[0], E[1], E[2], Hist);
  r2_scan_kernel<<<3, 256, 0, stream>>>(Hist, bbase, E[0], E[1], E[2]);
  r3b_scatter_kernel<<<3 * NBL, 256, 0, stream>>>(src[0], src[1], src[2], E[0], E[1], E[2],
                                                  Hist, tmp8);
  r4b_bucket_kernel<<<3 * NBKT, 256, 0, stream>>>(tmp8, bbase, E[0], E[1], E[2], cnt);
  rsqrt_inplace_kernel<<<cdiv(6 * N, B), B, 0, stream>>>(cnt, 6 * N);

  // ---- x -> bf16 (overlaps dead tmp region) ----
  f32_to_bf16_kernel<<<cdiv((long long)N * 64 / 4, B), B, 0, stream>>>(x, xb, N * 64 / 4);

  // ---- pack weights to MFMA B-fragment layout + bias sums ----
  for (int e = 0; e < 3; ++e) {
    pack_w_kernel<<<cdiv(64 * 96, B), B, 0, stream>>>(w0[e], B0p, 64, 96, e * 64, 6);
    pack_w_kernel<<<cdiv(96 * 128, B), B, 0, stream>>>(w1[e], B1p, 96, 128, e * 96, 8);
  }
  pack_w_kernel<<<cdiv(96 * 96, B), B, 0, stream>>>(fc0_w, fc0p, 96, 96, 0, 6);
  pack_w_kernel<<<cdiv(128 * 128, B), B, 0, stream>>>(fc1_w, fc1p, 128, 128, 0, 8);
  bias_sum_kernel<<<1, 96, 0, stream>>>(b0[0], b0[1], b0[2], b0s, 96);
  bias_sum_kernel<<<1, 128, 0, stream>>>(b1[0], b1[1], b1[2], b1s, 128);

  int es_off[3] = {0, E[0], E[0] + E[1]};

  // ---- layer 0: gather xb (bf16, D=64) into aggC [N][192], GEMM 192->96 ----
  for (int e = 0; e < 3; ++e)
    gather_kernel<64, 192><<<cdiv((long long)N * 64, B), B, 0, stream>>>(
        xb, row_ptr + e * (N + 1), es + es_off[e], rs + (2 * e) * N, rs + (2 * e + 1) * N,
        aggC, e * 64);
  gemm_kernel<192, 96, 0><<<N / 64, B, 0, stream>>>(aggC, B0p, b0s, hsum);
  hipMemsetAsync(stats, 0, 2 * 96 * 4, stream);
  bn_stats_kernel<96><<<2048, B, 0, stream>>>(hsum, stats);
  bn_finalize_kernel<96><<<1, 128, 0, stream>>>(stats, bn0_g, bn0_b, scale, shift);
  bnrelu_bf16_kernel<96><<<cdiv((long long)N * 96 / 4, B), B, 0, stream>>>(hsum, scale, shift, A0);
  gemm_kernel<96, 96, 1><<<N / 64, B, 0, stream>>>(A0, fc0p, fc0_b, h1);

  // ---- layer 1: gather h1 (bf16, D=96) into aggC [N][288], GEMM 288->128 ----
  for (int e = 0; e < 3; ++e)
    gather_kernel<96, 288><<<cdiv((long long)N * 64, B), B, 0, stream>>>(
        h1, row_ptr + e * (N + 1), es + es_off[e], rs + (2 * e) * N, rs + (2 * e + 1) * N,
        aggC, e * 96);
  gemm_kernel<288, 128, 0><<<N / 64, B, 0, stream>>>(aggC, B1p, b1s, hsum);
  hipMemsetAsync(stats, 0, 2 * 128 * 4, stream);
  bn_stats_kernel<128><<<2048, B, 0, stream>>>(hsum, stats);
  bn_finalize_kernel<128><<<1, 128, 0, stream>>>(stats, bn1_g, bn1_b, scale, shift);
  bnrelu_bf16_kernel<128><<<cdiv((long long)N * 128 / 4, B), B, 0, stream>>>(hsum, scale, shift, A1);
  gemm_kernel<128, 128, 0><<<N / 64, B, 0, stream>>>(A1, fc1p, fc1_b, (float*)d_out);
}

// Round 6
// 528.816 us; speedup vs baseline: 22.4829x; 1.2555x over previous
//
#include <hip/hip_runtime.h>
#include <hip/hip_bf16.h>

#define N_NODES 64000
#define BN_EPS 1e-5f
#define NBL 512      // radix blocks per type
#define NBKT 250     // coarse buckets = N_NODES / 256

typedef __attribute__((ext_vector_type(8))) short short8v;   // 8 bf16 (4 VGPRs)
typedef __attribute__((ext_vector_type(4))) float f32x4;

static inline int cdiv(long long a, int b) { return (int)((a + b - 1) / b); }

__device__ inline float bf2f(unsigned short u) {
  union { unsigned int i; float f; } v; v.i = ((unsigned int)u) << 16; return v.f;
}
__device__ inline unsigned short f2bf(float f) {
  __hip_bfloat16 h = __float2bfloat16(f);
  return *reinterpret_cast<unsigned short*>(&h);
}

// ================= atomic-free CSR build (two-level radix) =================
__global__ void r1_hist_kernel(const int* __restrict__ k0, const int* __restrict__ k1,
                               const int* __restrict__ k2, int E0, int E1, int E2,
                               int* __restrict__ Hist) {
  int t = blockIdx.x / NBL, blk = blockIdx.x - t * NBL;
  const int* key = t == 0 ? k0 : (t == 1 ? k1 : k2);
  int E = t == 0 ? E0 : (t == 1 ? E1 : E2);
  __shared__ int h[256];
  h[threadIdx.x] = 0;
  __syncthreads();
  int ch = (E + NBL - 1) / NBL;
  int lo = blk * ch, hi = min(lo + ch, E);
  for (int i = lo + threadIdx.x; i < hi; i += 256) atomicAdd(&h[key[i] >> 8], 1);
  __syncthreads();
  Hist[(t * NBL + blk) * 256 + threadIdx.x] = h[threadIdx.x];
}

__global__ void r2_scan_kernel(int* __restrict__ Hist, int* __restrict__ bbase,
                               int E0, int E1, int E2) {
  int t = blockIdx.x;
  int bin = threadIdx.x;
  int* H = Hist + (size_t)t * NBL * 256;
  int total = 0;
  for (int blk = 0; blk < NBL; ++blk) total += H[blk * 256 + bin];
  __shared__ int s[256];
  s[bin] = total;
  __syncthreads();
  for (int o = 1; o < 256; o <<= 1) {
    int a = (bin >= o) ? s[bin - o] : 0;
    __syncthreads();
    s[bin] += a;
    __syncthreads();
  }
  int base = s[bin] - total;
  if (bin <= NBKT) bbase[t * (NBKT + 1) + bin] = base;
  int run = base;
  for (int blk = 0; blk < NBL; ++blk) {
    int v = H[blk * 256 + bin];
    H[blk * 256 + bin] = run;
    run += v;
  }
}

__global__ void r3_scatter_kernel(const int* __restrict__ d0, const int* __restrict__ d1,
                                  const int* __restrict__ d2, const int* __restrict__ s0,
                                  const int* __restrict__ s1, const int* __restrict__ s2,
                                  int E0, int E1, int E2, const int* __restrict__ Hist,
                                  unsigned int* __restrict__ tmp) {
  int t = blockIdx.x / NBL, blk = blockIdx.x - t * NBL;
  const int* dst = t == 0 ? d0 : (t == 1 ? d1 : d2);
  const int* src = t == 0 ? s0 : (t == 1 ? s1 : s2);
  int E = t == 0 ? E0 : (t == 1 ? E1 : E2);
  unsigned int* tp = tmp + (t == 0 ? 0 : (t == 1 ? E0 : E0 + E1));
  __shared__ int off[256];
  off[threadIdx.x] = Hist[(t * NBL + blk) * 256 + threadIdx.x];
  __syncthreads();
  int ch = (E + NBL - 1) / NBL;
  int lo = blk * ch, hi = min(lo + ch, E);
  for (int i = lo + threadIdx.x; i < hi; i += 256) {
    int d = dst[i];
    int p = atomicAdd(&off[d >> 8], 1);
    tp[p] = ((unsigned)(d & 255) << 16) | (unsigned)src[i];
  }
}

__global__ void r4_bucket_kernel(const unsigned int* __restrict__ tmp,
                                 const int* __restrict__ bbase, int E0, int E1, int E2,
                                 unsigned short* __restrict__ es, int* __restrict__ row_ptr,
                                 int* __restrict__ cnt) {
  int t = blockIdx.x / NBKT, b = blockIdx.x - t * NBKT;
  const int* bb = bbase + t * (NBKT + 1);
  int teo = (t == 0 ? 0 : (t == 1 ? E0 : E0 + E1));
  int E = t == 0 ? E0 : (t == 1 ? E1 : E2);
  const unsigned int* tp = tmp + teo;
  unsigned short* esp = es + teo;
  int lo = bb[b], hi = bb[b + 1];
  __shared__ int c[256], s[256];
  c[threadIdx.x] = 0;
  __syncthreads();
  for (int i = lo + threadIdx.x; i < hi; i += 256) atomicAdd(&c[tp[i] >> 16], 1);
  __syncthreads();
  int v = c[threadIdx.x];
  s[threadIdx.x] = v;
  __syncthreads();
  for (int o = 1; o < 256; o <<= 1) {
    int a = (threadIdx.x >= o) ? s[threadIdx.x - o] : 0;
    __syncthreads();
    s[threadIdx.x] += a;
    __syncthreads();
  }
  int excl = s[threadIdx.x] - v;
  int node = b * 256 + threadIdx.x;
  cnt[(2 * t + 1) * N_NODES + node] = v;
  row_ptr[t * (N_NODES + 1) + node] = lo + excl;
  if (b == NBKT - 1 && threadIdx.x == 255) row_ptr[t * (N_NODES + 1) + N_NODES] = E;
  __syncthreads();
  s[threadIdx.x] = lo + excl;
  __syncthreads();
  for (int i = lo + threadIdx.x; i < hi; i += 256) {
    unsigned int w = tp[i];
    int p = atomicAdd(&s[w >> 16], 1);
    esp[p] = (unsigned short)(w & 0xFFFF);
  }
}

__global__ void r3b_scatter_kernel(const int* __restrict__ s0, const int* __restrict__ s1,
                                   const int* __restrict__ s2, int E0, int E1, int E2,
                                   const int* __restrict__ Hist, unsigned char* __restrict__ tmp8) {
  int t = blockIdx.x / NBL, blk = blockIdx.x - t * NBL;
  const int* src = t == 0 ? s0 : (t == 1 ? s1 : s2);
  int E = t == 0 ? E0 : (t == 1 ? E1 : E2);
  unsigned char* tp = tmp8 + (t == 0 ? 0 : (t == 1 ? E0 : E0 + E1));
  __shared__ int off[256];
  off[threadIdx.x] = Hist[(t * NBL + blk) * 256 + threadIdx.x];
  __syncthreads();
  int ch = (E + NBL - 1) / NBL;
  int lo = blk * ch, hi = min(lo + ch, E);
  for (int i = lo + threadIdx.x; i < hi; i += 256) {
    int sv = src[i];
    int p = atomicAdd(&off[sv >> 8], 1);
    tp[p] = (unsigned char)(sv & 255);
  }
}

__global__ void r4b_bucket_kernel(const unsigned char* __restrict__ tmp8,
                                  const int* __restrict__ bbase, int E0, int E1, int E2,
                                  int* __restrict__ cnt) {
  int t = blockIdx.x / NBKT, b = blockIdx.x - t * NBKT;
  const int* bb = bbase + t * (NBKT + 1);
  const unsigned char* tp = tmp8 + (t == 0 ? 0 : (t == 1 ? E0 : E0 + E1));
  int lo = bb[b], hi = bb[b + 1];
  __shared__ int c[256];
  c[threadIdx.x] = 0;
  __syncthreads();
  for (int i = lo + threadIdx.x; i < hi; i += 256) atomicAdd(&c[tp[i]], 1);
  __syncthreads();
  int node = b * 256 + threadIdx.x;
  cnt[(2 * t) * N_NODES + node] = c[threadIdx.x];
}

__global__ void rsqrt_inplace_kernel(void* buf, int n) {
  int i = blockIdx.x * blockDim.x + threadIdx.x;
  if (i < n) {
    int c = ((const int*)buf)[i];
    ((float*)buf)[i] = rsqrtf(fmaxf((float)c, 1.0f));
  }
}

__global__ void f32_to_bf16_kernel(const float* __restrict__ in, unsigned short* __restrict__ out,
                                   int n4) {
  int i = blockIdx.x * blockDim.x + threadIdx.x;
  if (i < n4) {
    float4 v = ((const float4*)in)[i];
    ushort4 o;
    o.x = f2bf(v.x); o.y = f2bf(v.y); o.z = f2bf(v.z); o.w = f2bf(v.w);
    ((ushort4*)out)[i] = o;
  }
}

__global__ void pack_w_kernel(const float* __restrict__ W, unsigned short* __restrict__ Bp,
                              int Ksrc, int NOUT, int k_off, int NB) {
  int idx = blockIdx.x * blockDim.x + threadIdx.x;
  if (idx >= Ksrc * NOUT) return;
  int kl = idx / NOUT, n = idx - kl * NOUT;
  int k = k_off + kl;
  int kb = k >> 5, nb = n >> 4;
  int lane = (((k >> 3) & 3) << 4) | (n & 15);
  int e = k & 7;
  Bp[(((kb * NB) + nb) * 64 + lane) * 8 + e] = f2bf(W[idx]);
}

__global__ void bias_sum_kernel(const float* a, const float* b, const float* c,
                                float* o, int n) {
  int i = blockIdx.x * blockDim.x + threadIdx.x;
  if (i < n) o[i] = a[i] + b[i] + c[i];
}

// ---- merged pull aggregation over all 3 types: wave w -> (type, node) ----
template<int D, int STR>
__global__ void gather3_kernel(const unsigned short* __restrict__ hb,
                               const int* __restrict__ row_ptr_base,
                               const unsigned short* __restrict__ es_base,
                               const float* __restrict__ rs, unsigned short* __restrict__ out,
                               int E0, int E01) {
  int gwid = (blockIdx.x * blockDim.x + threadIdx.x) >> 6;
  int lane = threadIdx.x & 63;
  if (gwid >= 3 * N_NODES) return;
  int t = gwid < N_NODES ? 0 : (gwid < 2 * N_NODES ? 1 : 2);
  int node = gwid - t * N_NODES;
  int eoff = t == 0 ? 0 : (t == 1 ? E0 : E01);
  const int* row_ptr = row_ptr_base + t * (N_NODES + 1);
  const unsigned short* es = es_base + eoff;
  const float* rs_out = rs + (2 * t) * N_NODES;
  const float* rs_in = rs + (2 * t + 1) * N_NODES;

  int lo = row_ptr[node], hi = row_ptr[node + 1];
  float acc0 = 0.f, acc1 = 0.f;
  const bool two = (D > 64) && (lane < D - 64);
  int e = lo;
  for (; e + 1 < hi; e += 2) {
    int s0 = es[e], s1 = es[e + 1];
    float w0 = rs_out[s0], w1 = rs_out[s1];
    acc0 += w0 * bf2f(hb[s0 * D + lane]) + w1 * bf2f(hb[s1 * D + lane]);
    if (two) acc1 += w0 * bf2f(hb[s0 * D + 64 + lane]) + w1 * bf2f(hb[s1 * D + 64 + lane]);
  }
  if (e < hi) {
    int s0 = es[e];
    float w0 = rs_out[s0];
    acc0 += w0 * bf2f(hb[s0 * D + lane]);
    if (two) acc1 += w0 * bf2f(hb[s0 * D + 64 + lane]);
  }
  float ri = rs_in[node];
  out[(long long)node * STR + t * D + lane] = f2bf(acc0 * ri);
  if (two) out[(long long)node * STR + t * D + 64 + lane] = f2bf(acc1 * ri);
}

// ---- MFMA GEMM with optional fused column-stats (sum, sumsq) epilogue ----
// out[M x NOUT] = A[M x K](bf16) @ Bp + bias;  stats[f] += colsum, stats[NOUT+f] += colsumsq
template<int K, int NOUT, int OUT_BF16, int STATS>
__global__ void gemm_kernel(const unsigned short* __restrict__ A,
                            const unsigned short* __restrict__ Bp,
                            const float* __restrict__ bias, void* __restrict__ outp,
                            float* __restrict__ stats) {
  constexpr int NB = NOUT / 16;
  constexpr int KB = K / 32;
  __shared__ float ls[STATS ? NOUT : 1], lq[STATS ? NOUT : 1];
  if (STATS) {
    for (int i = threadIdx.x; i < NOUT; i += blockDim.x) { ls[i] = 0.f; lq[i] = 0.f; }
    __syncthreads();
  }
  int wave = (blockIdx.x * blockDim.x + threadIdx.x) >> 6;
  int lane = threadIdx.x & 63;
  int row0 = wave * 16;
  int arow = row0 + (lane & 15);
  int kgrp = lane >> 4;
  f32x4 acc[NB];
#pragma unroll
  for (int i = 0; i < NB; ++i) acc[i] = (f32x4){0.f, 0.f, 0.f, 0.f};
  const short8v* ap = (const short8v*)(A + (long long)arow * K + kgrp * 8);
  const short8v* bp = (const short8v*)Bp;
#pragma unroll
  for (int kb = 0; kb < KB; ++kb) {
    short8v a = ap[kb * 4];
#pragma unroll
    for (int nb = 0; nb < NB; ++nb) {
      short8v b = bp[(kb * NB + nb) * 64 + lane];
      acc[nb] = __builtin_amdgcn_mfma_f32_16x16x32_bf16(a, b, acc[nb], 0, 0, 0);
    }
  }
  int r0 = (lane >> 4) * 4;
  int coll = lane & 15;
#pragma unroll
  for (int nb = 0; nb < NB; ++nb) {
    int col = nb * 16 + coll;
    float bv = bias[col];
    float s = 0.f, q = 0.f;
#pragma unroll
    for (int r = 0; r < 4; ++r) {
      long long row = row0 + r0 + r;
      float v = acc[nb][r] + bv;
      if (OUT_BF16) ((unsigned short*)outp)[row * NOUT + col] = f2bf(v);
      else ((float*)outp)[row * NOUT + col] = v;
      if (STATS) { s += v; q += v * v; }
    }
    if (STATS) {
      s += __shfl_xor(s, 16); q += __shfl_xor(q, 16);
      s += __shfl_xor(s, 32); q += __shfl_xor(q, 32);
      if (kgrp == 0) { atomicAdd(&ls[col], s); atomicAdd(&lq[col], q); }
    }
  }
  if (STATS) {
    __syncthreads();
    if (threadIdx.x < NOUT) {
      atomicAdd(&stats[threadIdx.x], ls[threadIdx.x]);
      atomicAdd(&stats[NOUT + threadIdx.x], lq[threadIdx.x]);
    }
  }
}

// ---- FC GEMM with fused BN->ReLU->bf16 on the f32 A operand ----
template<int K, int NOUT, int OUT_BF16>
__global__ void fcgemm_kernel(const float* __restrict__ Af,
                              const unsigned short* __restrict__ Bp,
                              const float* __restrict__ scale, const float* __restrict__ shift,
                              const float* __restrict__ bias, void* __restrict__ outp) {
  constexpr int NB = NOUT / 16;
  constexpr int KB = K / 32;
  int wave = (blockIdx.x * blockDim.x + threadIdx.x) >> 6;
  int lane = threadIdx.x & 63;
  int row0 = wave * 16;
  int arow = row0 + (lane & 15);
  int kgrp = lane >> 4;
  f32x4 acc[NB];
#pragma unroll
  for (int i = 0; i < NB; ++i) acc[i] = (f32x4){0.f, 0.f, 0.f, 0.f};
  const float* ap = Af + (long long)arow * K + kgrp * 8;
  const short8v* bp = (const short8v*)Bp;
#pragma unroll
  for (int kb = 0; kb < KB; ++kb) {
    int k0 = kb * 32;
    float4 v0 = *(const float4*)(ap + k0);
    float4 v1 = *(const float4*)(ap + k0 + 4);
    int kk = k0 + kgrp * 8;
    short8v a;
    a[0] = (short)f2bf(fmaxf(fmaf(v0.x, scale[kk + 0], shift[kk + 0]), 0.f));
    a[1] = (short)f2bf(fmaxf(fmaf(v0.y, scale[kk + 1], shift[kk + 1]), 0.f));
    a[2] = (short)f2bf(fmaxf(fmaf(v0.z, scale[kk + 2], shift[kk + 2]), 0.f));
    a[3] = (short)f2bf(fmaxf(fmaf(v0.w, scale[kk + 3], shift[kk + 3]), 0.f));
    a[4] = (short)f2bf(fmaxf(fmaf(v1.x, scale[kk + 4], shift[kk + 4]), 0.f));
    a[5] = (short)f2bf(fmaxf(fmaf(v1.y, scale[kk + 5], shift[kk + 5]), 0.f));
    a[6] = (short)f2bf(fmaxf(fmaf(v1.z, scale[kk + 6], shift[kk + 6]), 0.f));
    a[7] = (short)f2bf(fmaxf(fmaf(v1.w, scale[kk + 7], shift[kk + 7]), 0.f));
#pragma unroll
    for (int nb = 0; nb < NB; ++nb) {
      short8v b = bp[(kb * NB + nb) * 64 + lane];
      acc[nb] = __builtin_amdgcn_mfma_f32_16x16x32_bf16(a, b, acc[nb], 0, 0, 0);
    }
  }
  int r0 = (lane >> 4) * 4;
  int coll = lane & 15;
#pragma unroll
  for (int nb = 0; nb < NB; ++nb) {
    int col = nb * 16 + coll;
    float bv = bias[col];
#pragma unroll
    for (int r = 0; r < 4; ++r) {
      long long row = row0 + r0 + r;
      float v = acc[nb][r] + bv;
      if (OUT_BF16) ((unsigned short*)outp)[row * NOUT + col] = f2bf(v);
      else ((float*)outp)[row * NOUT + col] = v;
    }
  }
}

// NOTE: fcgemm's A-load applies scale/shift at index kk = kb*32 + kgrp*8 + e,
// but v0/v1 were loaded from ap = row + kgrp*8 + kb*32 ... same offset. Good.

template<int D>
__global__ void bn_finalize_kernel(const float* __restrict__ stats, const float* __restrict__ g,
                                   const float* __restrict__ be, float* scale, float* shift) {
  int f = threadIdx.x;
  if (f < D) {
    float mean = stats[f] * (1.0f / N_NODES);
    float var = stats[D + f] * (1.0f / N_NODES) - mean * mean;
    float rstd = rsqrtf(var + BN_EPS);
    float sc = g[f] * rstd;
    scale[f] = sc;
    shift[f] = be[f] - mean * sc;
  }
}

extern "C" void kernel_launch(void* const* d_in, const int* in_sizes, int n_in,
                              void* d_out, int out_size, void* d_ws, size_t ws_size,
                              hipStream_t stream) {
  const int N = N_NODES;
  const float* x = (const float*)d_in[0];
  const int* src[3] = {(const int*)d_in[1], (const int*)d_in[3], (const int*)d_in[5]};
  const int* dst[3] = {(const int*)d_in[2], (const int*)d_in[4], (const int*)d_in[6]};
  const int E[3] = {in_sizes[1], in_sizes[3], in_sizes[5]};
  const int E_tot = E[0] + E[1] + E[2];

  const float* w0[3] = {(const float*)d_in[7], (const float*)d_in[9], (const float*)d_in[11]};
  const float* b0[3] = {(const float*)d_in[8], (const float*)d_in[10], (const float*)d_in[12]};
  const float* bn0_g = (const float*)d_in[13];
  const float* bn0_b = (const float*)d_in[14];
  const float* fc0_w = (const float*)d_in[15];
  const float* fc0_b = (const float*)d_in[16];
  const float* w1[3] = {(const float*)d_in[17], (const float*)d_in[19], (const float*)d_in[21]};
  const float* b1[3] = {(const float*)d_in[18], (const float*)d_in[20], (const float*)d_in[22]};
  const float* bn1_g = (const float*)d_in[23];
  const float* bn1_b = (const float*)d_in[24];
  const float* fc1_w = (const float*)d_in[25];
  const float* fc1_b = (const float*)d_in[26];

  // ---- workspace layout ----
  char* p = (char*)d_ws;
  auto alloc = [&](size_t bytes) { char* r = p; p += (bytes + 255) & ~255ULL; return r; };
  int* cnt = (int*)alloc((size_t)6 * N * 4);                  // -> rs floats after rsqrt
  int* row_ptr = (int*)alloc((size_t)3 * (N + 1) * 4);
  int* bbase = (int*)alloc((size_t)3 * (NBKT + 1) * 4);
  unsigned short* es = (unsigned short*)alloc((size_t)E_tot * 2);
  unsigned short* wpk = (unsigned short*)alloc((size_t)(18432 + 36864 + 9216 + 16384) * 2);
  float* b0s = (float*)alloc(96 * 4);
  float* b1s = (float*)alloc(128 * 4);
  float* stats = (float*)alloc(256 * 4);
  float* scale = (float*)alloc(128 * 4);
  float* shift = (float*)alloc(128 * 4);
  unsigned short* aggC = (unsigned short*)alloc((size_t)N * 288 * 2);
  float* hsum = (float*)alloc((size_t)N * 128 * 4);            // also hosts tmp/Hist/xb early
  unsigned short* h1 = (unsigned short*)alloc((size_t)N * 96 * 2);

  unsigned short* B0p = wpk;                          // 192x96
  unsigned short* B1p = wpk + 18432;                  // 288x128
  unsigned short* fc0p = wpk + 18432 + 36864;         // 96x96
  unsigned short* fc1p = wpk + 18432 + 36864 + 9216;  // 128x128
  float* rs = (float*)cnt;

  // transient aliases inside hsum region (dead before gemm0 writes hsum)
  unsigned int* tmp = (unsigned int*)hsum;
  unsigned char* tmp8 = (unsigned char*)hsum;
  int* Hist = (int*)((char*)hsum + ((size_t)9 << 20));
  unsigned short* xb = (unsigned short*)hsum;

  const int B = 256;

  // ---- CSR build (dst sort) + cnt_in ----
  r1_hist_kernel<<<3 * NBL, 256, 0, stream>>>(dst[0], dst[1], dst[2], E[0], E[1], E[2], Hist);
  r2_scan_kernel<<<3, 256, 0, stream>>>(Hist, bbase, E[0], E[1], E[2]);
  r3_scatter_kernel<<<3 * NBL, 256, 0, stream>>>(dst[0], dst[1], dst[2], src[0], src[1], src[2],
                                                 E[0], E[1], E[2], Hist, tmp);
  r4_bucket_kernel<<<3 * NBKT, 256, 0, stream>>>(tmp, bbase, E[0], E[1], E[2], es, row_ptr, cnt);
  // ---- out-degree counts (src) ----
  r1_hist_kernel<<<3 * NBL, 256, 0, stream>>>(src[0], src[1], src[2], E[0], E[1], E[2], Hist);
  r2_scan_kernel<<<3, 256, 0, stream>>>(Hist, bbase, E[0], E[1], E[2]);
  r3b_scatter_kernel<<<3 * NBL, 256, 0, stream>>>(src[0], src[1], src[2], E[0], E[1], E[2],
                                                  Hist, tmp8);
  r4b_bucket_kernel<<<3 * NBKT, 256, 0, stream>>>(tmp8, bbase, E[0], E[1], E[2], cnt);
  rsqrt_inplace_kernel<<<cdiv(6 * N, B), B, 0, stream>>>(cnt, 6 * N);

  // ---- x -> bf16 (in dead tmp region) ----
  f32_to_bf16_kernel<<<cdiv((long long)N * 64 / 4, B), B, 0, stream>>>(x, xb, N * 64 / 4);

  // ---- pack weights + bias sums ----
  for (int e = 0; e < 3; ++e) {
    pack_w_kernel<<<cdiv(64 * 96, B), B, 0, stream>>>(w0[e], B0p, 64, 96, e * 64, 6);
    pack_w_kernel<<<cdiv(96 * 128, B), B, 0, stream>>>(w1[e], B1p, 96, 128, e * 96, 8);
  }
  pack_w_kernel<<<cdiv(96 * 96, B), B, 0, stream>>>(fc0_w, fc0p, 96, 96, 0, 6);
  pack_w_kernel<<<cdiv(128 * 128, B), B, 0, stream>>>(fc1_w, fc1p, 128, 128, 0, 8);
  bias_sum_kernel<<<1, 96, 0, stream>>>(b0[0], b0[1], b0[2], b0s, 96);
  bias_sum_kernel<<<1, 128, 0, stream>>>(b1[0], b1[1], b1[2], b1s, 128);

  // ---- layer 0: merged gather (bf16 x, D=64) -> aggC [N][192]; GEMM+stats; FC fused BN ----
  hipMemsetAsync(stats, 0, 2 * 96 * 4, stream);
  gather3_kernel<64, 192><<<cdiv((long long)3 * N * 64, B), B, 0, stream>>>(
      xb, row_ptr, es, rs, aggC, E[0], E[0] + E[1]);
  gemm_kernel<192, 96, 0, 1><<<N / 64, B, 0, stream>>>(aggC, B0p, b0s, hsum, stats);
  bn_finalize_kernel<96><<<1, 128, 0, stream>>>(stats, bn0_g, bn0_b, scale, shift);
  fcgemm_kernel<96, 96, 1><<<N / 64, B, 0, stream>>>(hsum, fc0p, scale, shift, fc0_b, h1);

  // ---- layer 1: merged gather (bf16 h1, D=96) -> aggC [N][288]; GEMM+stats; FC fused BN ----
  hipMemsetAsync(stats, 0, 2 * 128 * 4, stream);
  gather3_kernel<96, 288><<<cdiv((long long)3 * N * 64, B), B, 0, stream>>>(
      h1, row_ptr, es, rs, aggC, E[0], E[0] + E[1]);
  gemm_kernel<288, 128, 0, 1><<<N / 64, B, 0, stream>>>(aggC, B1p, b1s, hsum, stats);
  bn_finalize_kernel<128><<<1, 128, 0, stream>>>(stats, bn1_g, bn1_b, scale, shift);
  fcgemm_kernel<128, 128, 0><<<N / 64, B, 0, stream>>>(hsum, fc1p, scale, shift, fc1_b,
                                                       (float*)d_out);
}